// Round 5
// baseline (260.155 us; speedup 1.0000x reference)
//
#include <hip/hip_runtime.h>

#define B_ 16
#define NC 1024
#define NF 4096
#define CIN 256
#define CSKIP 128
#define CHID 256
#define MTOT (B_ * NF)   // 65536
#define EPS_ 1e-16f

typedef _Float16 f16;
typedef __attribute__((ext_vector_type(8))) _Float16 f16x8;
typedef __attribute__((ext_vector_type(4))) _Float16 f16x4;
typedef __attribute__((ext_vector_type(2))) _Float16 f16x2;
typedef __attribute__((ext_vector_type(4))) float f32x4;

// ---------------- kNN top-3, coarse dim split 4x for occupancy ----------------
__global__ __launch_bounds__(256) void knn_kernel(
    const float* __restrict__ pos, const float* __restrict__ pos_skip,
    int* __restrict__ idx3, float* __restrict__ w3)
{
    __shared__ float4 cpos[NC];          // 16 KB
    __shared__ float  cd[64 * 12];       // 3 KB
    __shared__ int    ci[64 * 12];       // 3 KB

    const int b  = blockIdx.x >> 6;
    const int fb = blockIdx.x & 63;
    const float* cp = pos + (size_t)b * NC * 3;
    for (int i = threadIdx.x; i < NC; i += 256)
        cpos[i] = make_float4(cp[i * 3], cp[i * 3 + 1], cp[i * 3 + 2], 0.0f);
    __syncthreads();

    const int fl = threadIdx.x & 63;
    const int q  = threadIdx.x >> 6;
    const int f  = b * NF + fb * 64 + fl;
    const float px = pos_skip[f * 3 + 0];
    const float py = pos_skip[f * 3 + 1];
    const float pz = pos_skip[f * 3 + 2];

    float d0 = 3.4e38f, d1 = 3.4e38f, d2 = 3.4e38f;
    int   i0 = 0, i1 = 0, i2 = 0;
    const int jbase = q << 8;
#pragma unroll 4
    for (int jj = 0; jj < 256; ++jj) {
        const int j = jbase + jj;
        float4 c = cpos[j];
        float dx = px - c.x, dy = py - c.y, dz = pz - c.z;
        float d = fmaf(dx, dx, fmaf(dy, dy, dz * dz));
        if (d < d2) {
            if (d < d1) {
                d2 = d1; i2 = i1;
                if (d < d0) { d1 = d0; i1 = i0; d0 = d; i0 = j; }
                else        { d1 = d;  i1 = j; }
            } else { d2 = d; i2 = j; }
        }
    }
    const int cb = fl * 12 + q * 3;
    cd[cb + 0] = d0; cd[cb + 1] = d1; cd[cb + 2] = d2;
    ci[cb + 0] = i0; ci[cb + 1] = i1; ci[cb + 2] = i2;
    __syncthreads();

    // quarters merged in ascending-index order, strict < insert == top_k ties
    if (threadIdx.x < 64) {
        float e0 = 3.4e38f, e1 = 3.4e38f, e2 = 3.4e38f;
        int   j0 = 0, j1 = 0, j2 = 0;
#pragma unroll
        for (int s = 0; s < 12; ++s) {
            const float d = cd[fl * 12 + s];
            const int   j = ci[fl * 12 + s];
            if (d < e2) {
                if (d < e1) {
                    e2 = e1; j2 = j1;
                    if (d < e0) { e1 = e0; j1 = j0; e0 = d; j0 = j; }
                    else        { e1 = d;  j1 = j; }
                } else { e2 = d; j2 = j; }
            }
        }
        float w0 = 1.0f / fmaxf(e0, EPS_);
        float w1 = 1.0f / fmaxf(e1, EPS_);
        float w2 = 1.0f / fmaxf(e2, EPS_);
        float inv = 1.0f / (w0 + w1 + w2);
        idx3[f * 3 + 0] = b * NC + j0;
        idx3[f * 3 + 1] = b * NC + j1;
        idx3[f * 3 + 2] = b * NC + j2;
        w3[f * 3 + 0] = w0 * inv;
        w3[f * 3 + 1] = w1 * inv;
        w3[f * 3 + 2] = w2 * inv;
    }
}

// ---------------- weights: W1t[n][k]; W2t[n][j] with K-permutation pi ----------------
// h1 is stored K-permuted: stored j = base64 + q*4 + n  holds logical k = base64 + n*16 + q.
// So W2t[n2][j] = W2[k(j)][n2] with k(j) = (j&~63) + (j&3)*16 + ((j>>2)&15).
__global__ __launch_bounds__(256) void wconv_kernel(
    const float* __restrict__ W1, const float* __restrict__ W2,
    f16* __restrict__ W1t, f16* __restrict__ W2t)
{
    const int t = blockIdx.x * 256 + threadIdx.x;
    if (t < 384 * 256) {
        const int k = t >> 8, n = t & 255;
        W1t[n * 384 + k] = (f16)W1[t];
    } else if (t < 384 * 256 + 256 * 256) {
        const int u = t - 384 * 256;
        const int n = u >> 8, j = u & 255;
        const int k = (j & ~63) + ((j & 3) << 4) + ((j >> 2) & 15);
        W2t[n * 256 + j] = (f16)W2[k * 256 + n];
    }
}

// ---------------- async global->LDS, 16B per lane, linear dest ----------------
__device__ __forceinline__ void gload16(const void* g, void* l)
{
    __builtin_amdgcn_global_load_lds(
        (const __attribute__((address_space(1))) unsigned int*)g,
        (__attribute__((address_space(3))) unsigned int*)l, 16, 0, 0);
}

// ---------------- fused layer-1: gather-interp-staged MFMA GEMM ----------------
// h1[M][256] = relu([interp|x_skip][M][384] @ W1t^T + b1), stored K-permuted, f16.
// BM=128, BN=256 (full N), BK=64, 4 waves (2x2), wave tile 64x128 (4x8 frags).
// A staged in-register (gather+interp or x_skip cvt) -> swizzled ds_write_b128;
// B staged via global_load_lds (linear dest, inverse-swizzled source).
__global__ __launch_bounds__(256, 2) void gemm1_fused(
    const float* __restrict__ x, const float* __restrict__ x_skip,
    const int* __restrict__ idx3, const float* __restrict__ w3,
    const f16* __restrict__ W1t, const float* __restrict__ bias,
    f16* __restrict__ h1)
{
    __shared__ f16 As[128 * 64];   // 16 KB
    __shared__ f16 Bs[256 * 64];   // 32 KB
    const int tid  = threadIdx.x;
    const int lane = tid & 63;
    const int wid  = tid >> 6;
    const int wr   = wid >> 1, wc = wid & 1;
    const int m0   = blockIdx.x * 128;

    // A-staging role: 2 threads per row, 32 channels each
    const int srow = tid >> 1;
    const int scg  = tid & 1;
    const int rowg = m0 + srow;
    const int gi0 = idx3[rowg * 3 + 0];
    const int gi1 = idx3[rowg * 3 + 1];
    const int gi2 = idx3[rowg * 3 + 2];
    const float gw0 = w3[rowg * 3 + 0];
    const float gw1 = w3[rowg * 3 + 1];
    const float gw2 = w3[rowg * 3 + 2];

    // B-staging coords (global_load_lds): chunk c = wid*8 + r covers Bs rows [c*8, c*8+8)
    const int srow_l = lane >> 3;
    const int kch    = (lane & 7) ^ ((lane >> 3) & 7);

    f32x4 acc[4][8] = {};

    for (int k0 = 0; k0 < 384; k0 += 64) {
        // B: 32 chunks of 1KB, 8 per wave
#pragma unroll
        for (int r = 0; r < 8; ++r) {
            const int c = (wid << 3) + r;
            const int row = (c << 3) + srow_l;
            gload16(W1t + (size_t)row * 384 + k0 + kch * 8,
                    (char*)Bs + (c << 10));
        }
        // A: compute 32 channels, pack f16, swizzled ds_write
        float v[32];
        if (k0 < 256) {
            const float* p0 = x + (size_t)gi0 * CIN + k0 + scg * 32;
            const float* p1 = x + (size_t)gi1 * CIN + k0 + scg * 32;
            const float* p2 = x + (size_t)gi2 * CIN + k0 + scg * 32;
#pragma unroll
            for (int j = 0; j < 8; ++j) {
                float4 a = ((const float4*)p0)[j];
                float4 b = ((const float4*)p1)[j];
                float4 c = ((const float4*)p2)[j];
                v[j * 4 + 0] = gw0 * a.x + gw1 * b.x + gw2 * c.x;
                v[j * 4 + 1] = gw0 * a.y + gw1 * b.y + gw2 * c.y;
                v[j * 4 + 2] = gw0 * a.z + gw1 * b.z + gw2 * c.z;
                v[j * 4 + 3] = gw0 * a.w + gw1 * b.w + gw2 * c.w;
            }
        } else {
            const float* ps = x_skip + (size_t)rowg * CSKIP + (k0 - 256) + scg * 32;
#pragma unroll
            for (int j = 0; j < 8; ++j) {
                float4 a = ((const float4*)ps)[j];
                v[j * 4 + 0] = a.x; v[j * 4 + 1] = a.y;
                v[j * 4 + 2] = a.z; v[j * 4 + 3] = a.w;
            }
        }
#pragma unroll
        for (int j = 0; j < 4; ++j) {
            f16x8 hh;
#pragma unroll
            for (int t2 = 0; t2 < 8; ++t2) hh[t2] = (f16)v[j * 8 + t2];
            const int slog  = scg * 4 + j;
            const int sphys = slog ^ (srow & 7);
            *(f16x8*)((char*)As + srow * 128 + sphys * 16) = hh;
        }
        __syncthreads();

#pragma unroll
        for (int h = 0; h < 2; ++h) {
            f16x8 aF[4];
#pragma unroll
            for (int m = 0; m < 4; ++m) {
                const int row  = wr * 64 + m * 16 + (lane & 15);
                const int kg   = (h << 2) + (lane >> 4);
                const int slot = kg ^ (row & 7);
                aF[m] = *(const f16x8*)((const char*)As + row * 128 + slot * 16);
            }
#pragma unroll
            for (int n = 0; n < 8; ++n) {
                const int row  = wc * 128 + n * 16 + (lane & 15);
                const int kg   = (h << 2) + (lane >> 4);
                const int slot = kg ^ (row & 7);
                f16x8 bF = *(const f16x8*)((const char*)Bs + row * 128 + slot * 16);
#pragma unroll
                for (int m = 0; m < 4; ++m)
                    acc[m][n] = __builtin_amdgcn_mfma_f32_16x16x32_f16(
                        aF[m], bF, acc[m][n], 0, 0, 0);
            }
        }
        __syncthreads();
    }

    // epilogue: bias+relu, pack 4 n-frag values (cols n*16+q) -> stored j=q*4+n
    const int qq = lane & 15;
#pragma unroll
    for (int m = 0; m < 4; ++m) {
        const int rb = wr * 64 + m * 16 + ((lane >> 4) << 2);
#pragma unroll
        for (int r = 0; r < 4; ++r) {
            const int rg = m0 + rb + r;
#pragma unroll
            for (int g = 0; g < 2; ++g) {
                f16x4 hv;
#pragma unroll
                for (int n = 0; n < 4; ++n) {
                    const int col = wc * 128 + g * 64 + n * 16 + qq;
                    hv[n] = (f16)fmaxf(acc[m][g * 4 + n][r] + bias[col], 0.0f);
                }
                *(f16x4*)&h1[(size_t)rg * 256 + wc * 128 + g * 64 + qq * 4] = hv;
            }
        }
    }
}

// ---------------- layer-2 MFMA GEMM (unchanged structure) ----------------
template <int K, bool OUT_F16>
__global__ __launch_bounds__(256) void gemm_f16_mfma(
    const f16* __restrict__ A, const f16* __restrict__ Bt,
    const float* __restrict__ bias, void* __restrict__ Cout)
{
    __shared__ f16 As[128 * 64];   // 16 KB
    __shared__ f16 Bs[128 * 64];   // 16 KB
    const int tid  = threadIdx.x;
    const int lane = tid & 63;
    const int wid  = tid >> 6;
    const int wr   = wid >> 1, wc = wid & 1;
    const int m0 = blockIdx.x * 128;
    const int n0 = blockIdx.y * 128;

    const int srow_l = lane >> 3;
    const int kch    = (lane & 7) ^ ((lane >> 3) & 7);

    f32x4 acc[4][4] = {};

    for (int k0 = 0; k0 < K; k0 += 64) {
#pragma unroll
        for (int r = 0; r < 4; ++r) {
            const int c = (wid << 2) + r;
            const int row = (c << 3) + srow_l;
            gload16(A  + (size_t)(m0 + row) * K + k0 + kch * 8,
                    (char*)As + (c << 10));
            gload16(Bt + (size_t)(n0 + row) * K + k0 + kch * 8,
                    (char*)Bs + (c << 10));
        }
        __syncthreads();

#pragma unroll
        for (int h = 0; h < 2; ++h) {
            f16x8 aF[4], bF[4];
#pragma unroll
            for (int m = 0; m < 4; ++m) {
                const int row  = wr * 64 + m * 16 + (lane & 15);
                const int kg   = (h << 2) + (lane >> 4);
                const int slot = kg ^ (row & 7);
                aF[m] = *(const f16x8*)((const char*)As + row * 128 + slot * 16);
            }
#pragma unroll
            for (int n = 0; n < 4; ++n) {
                const int row  = wc * 64 + n * 16 + (lane & 15);
                const int kg   = (h << 2) + (lane >> 4);
                const int slot = kg ^ (row & 7);
                bF[n] = *(const f16x8*)((const char*)Bs + row * 128 + slot * 16);
            }
#pragma unroll
            for (int m = 0; m < 4; ++m)
#pragma unroll
                for (int n = 0; n < 4; ++n)
                    acc[m][n] = __builtin_amdgcn_mfma_f32_16x16x32_f16(
                        aF[m], bF[n], acc[m][n], 0, 0, 0);
        }
        __syncthreads();
    }

#pragma unroll
    for (int m = 0; m < 4; ++m) {
#pragma unroll
        for (int n = 0; n < 4; ++n) {
            const int col = n0 + wc * 64 + n * 16 + (lane & 15);
            const float bv = bias[col];
#pragma unroll
            for (int r = 0; r < 4; ++r) {
                const int row = m0 + wr * 64 + m * 16 + ((lane >> 4) << 2) + r;
                const float v = fmaxf(acc[m][n][r] + bv, 0.0f);
                if (OUT_F16)
                    ((f16*)Cout)[(size_t)row * 256 + col] = (f16)v;
                else
                    ((float*)Cout)[(size_t)row * 256 + col] = v;
            }
        }
    }
}

// ---------------- tail: pos_skip passthrough + batch_skip as float ----------------
__global__ __launch_bounds__(256) void copy_tail_kernel(
    const float* __restrict__ pos_skip, const int* __restrict__ batch_skip,
    float* __restrict__ out)
{
    const int i = blockIdx.x * 256 + threadIdx.x;
    const int npos = MTOT * 3;
    if (i < npos)               out[i] = pos_skip[i];
    else if (i < npos + MTOT)   out[i] = (float)batch_skip[i - npos];
}

extern "C" void kernel_launch(void* const* d_in, const int* in_sizes, int n_in,
                              void* d_out, int out_size, void* d_ws, size_t ws_size,
                              hipStream_t stream)
{
    const float* x        = (const float*)d_in[0];
    const float* pos      = (const float*)d_in[1];
    const float* x_skip   = (const float*)d_in[2];
    const float* pos_skip = (const float*)d_in[3];
    const float* W1       = (const float*)d_in[4];
    const float* b1       = (const float*)d_in[5];
    const float* W2       = (const float*)d_in[6];
    const float* b2       = (const float*)d_in[7];
    const int*   batch_skip = (const int*)d_in[9];
    float* out = (float*)d_out;

    char* ws = (char*)d_ws;
    int*   idx3 = (int*)ws;                               // 768 KB
    float* w3   = (float*)(ws + (1u << 20));              // 768 KB
    f16*   W1t  = (f16*)(ws + (2u << 20));                // 192 KB
    f16*   W2t  = (f16*)(ws + (2u << 20) + (512u << 10)); // 128 KB
    f16*   h1   = (f16*)(ws + (4u << 20));                // 32 MB

    knn_kernel<<<MTOT / 64, 256, 0, stream>>>(pos, pos_skip, idx3, w3);
    wconv_kernel<<<640, 256, 0, stream>>>(W1, W2, W1t, W2t);

    gemm1_fused<<<MTOT / 128, 256, 0, stream>>>(x, x_skip, idx3, w3, W1t, b1, h1);

    dim3 g2(MTOT / 128, 2);
    gemm_f16_mfma<256, false><<<g2, 256, 0, stream>>>(h1, W2t, b2, out);

    copy_tail_kernel<<<1024, 256, 0, stream>>>(pos_skip, batch_skip,
                                               out + (size_t)MTOT * CHID);
}

// Round 6
// 218.989 us; speedup vs baseline: 1.1880x; 1.1880x over previous
//
#include <hip/hip_runtime.h>

#define B_ 16
#define NC 1024
#define NF 4096
#define CIN 256
#define CSKIP 128
#define CHID 256
#define MTOT (B_ * NF)   // 65536
#define EPS_ 1e-16f

typedef _Float16 f16;
typedef __attribute__((ext_vector_type(8))) _Float16 f16x8;
typedef __attribute__((ext_vector_type(4))) _Float16 f16x4;
typedef __attribute__((ext_vector_type(2))) _Float16 f16x2;
typedef __attribute__((ext_vector_type(4))) float f32x4;

// ---------------- kNN top-3, coarse dim split 4x for occupancy ----------------
__global__ __launch_bounds__(256) void knn_kernel(
    const float* __restrict__ pos, const float* __restrict__ pos_skip,
    int* __restrict__ idx3, float* __restrict__ w3)
{
    __shared__ float4 cpos[NC];          // 16 KB
    __shared__ float  cd[64 * 12];       // 3 KB
    __shared__ int    ci[64 * 12];       // 3 KB

    const int b  = blockIdx.x >> 6;
    const int fb = blockIdx.x & 63;
    const float* cp = pos + (size_t)b * NC * 3;
    for (int i = threadIdx.x; i < NC; i += 256)
        cpos[i] = make_float4(cp[i * 3], cp[i * 3 + 1], cp[i * 3 + 2], 0.0f);
    __syncthreads();

    const int fl = threadIdx.x & 63;
    const int q  = threadIdx.x >> 6;
    const int f  = b * NF + fb * 64 + fl;
    const float px = pos_skip[f * 3 + 0];
    const float py = pos_skip[f * 3 + 1];
    const float pz = pos_skip[f * 3 + 2];

    float d0 = 3.4e38f, d1 = 3.4e38f, d2 = 3.4e38f;
    int   i0 = 0, i1 = 0, i2 = 0;
    const int jbase = q << 8;
#pragma unroll 4
    for (int jj = 0; jj < 256; ++jj) {
        const int j = jbase + jj;
        float4 c = cpos[j];
        float dx = px - c.x, dy = py - c.y, dz = pz - c.z;
        float d = fmaf(dx, dx, fmaf(dy, dy, dz * dz));
        if (d < d2) {
            if (d < d1) {
                d2 = d1; i2 = i1;
                if (d < d0) { d1 = d0; i1 = i0; d0 = d; i0 = j; }
                else        { d1 = d;  i1 = j; }
            } else { d2 = d; i2 = j; }
        }
    }
    const int cb = fl * 12 + q * 3;
    cd[cb + 0] = d0; cd[cb + 1] = d1; cd[cb + 2] = d2;
    ci[cb + 0] = i0; ci[cb + 1] = i1; ci[cb + 2] = i2;
    __syncthreads();

    // quarters merged in ascending-index order, strict < insert == top_k ties
    if (threadIdx.x < 64) {
        float e0 = 3.4e38f, e1 = 3.4e38f, e2 = 3.4e38f;
        int   j0 = 0, j1 = 0, j2 = 0;
#pragma unroll
        for (int s = 0; s < 12; ++s) {
            const float d = cd[fl * 12 + s];
            const int   j = ci[fl * 12 + s];
            if (d < e2) {
                if (d < e1) {
                    e2 = e1; j2 = j1;
                    if (d < e0) { e1 = e0; j1 = j0; e0 = d; j0 = j; }
                    else        { e1 = d;  j1 = j; }
                } else { e2 = d; j2 = j; }
            }
        }
        float w0 = 1.0f / fmaxf(e0, EPS_);
        float w1 = 1.0f / fmaxf(e1, EPS_);
        float w2 = 1.0f / fmaxf(e2, EPS_);
        float inv = 1.0f / (w0 + w1 + w2);
        idx3[f * 3 + 0] = b * NC + j0;
        idx3[f * 3 + 1] = b * NC + j1;
        idx3[f * 3 + 2] = b * NC + j2;
        w3[f * 3 + 0] = w0 * inv;
        w3[f * 3 + 1] = w1 * inv;
        w3[f * 3 + 2] = w2 * inv;
    }
}

// ---------------- weights -> f16 transposed: W1aT[256][256], W1bT[256][128], W2T[256][256] ----------------
__global__ __launch_bounds__(256) void wconv_kernel(
    const float* __restrict__ W1, const float* __restrict__ W2,
    f16* __restrict__ W1aT, f16* __restrict__ W1bT, f16* __restrict__ W2T)
{
    const int t = blockIdx.x * 256 + threadIdx.x;
    if (t < 256 * 256) {
        const int k = t >> 8, n = t & 255;
        W1aT[n * 256 + k] = (f16)W1[k * 256 + n];
    } else if (t < 256 * 256 + 128 * 256) {
        const int u = t - 256 * 256;
        const int k = u >> 8, n = u & 255;            // k in [0,128)
        W1bT[n * 128 + k] = (f16)W1[(256 + k) * 256 + n];
    } else if (t < 256 * 256 + 128 * 256 + 256 * 256) {
        const int u = t - 256 * 256 - 128 * 256;
        const int k = u >> 8, n = u & 255;
        W2T[n * 256 + k] = (f16)W2[k * 256 + n];
    }
}

// ---------------- async global->LDS, 16B per lane, linear dest ----------------
__device__ __forceinline__ void gload16(const void* g, void* l)
{
    __builtin_amdgcn_global_load_lds(
        (const __attribute__((address_space(1))) unsigned int*)g,
        (__attribute__((address_space(3))) unsigned int*)l, 16, 0, 0);
}

// ---------------- GEMM, A f32 reg-staged(+cvt), B f16 gload_lds: C_f16 = A @ Bt^T ----------------
// BM=128, BN=256 (full N), BK=64, 4 waves (2x2), wave tile 64x128. No bias/relu.
template <int K>
__global__ __launch_bounds__(256, 2) void gemm_regA(
    const float* __restrict__ A, const f16* __restrict__ Bt,
    f16* __restrict__ C)
{
    __shared__ f16 As[128 * 64];   // 16 KB
    __shared__ f16 Bs[256 * 64];   // 32 KB
    const int tid  = threadIdx.x;
    const int lane = tid & 63;
    const int wid  = tid >> 6;
    const int wr   = wid >> 1, wc = wid & 1;
    const int m0   = blockIdx.x * 128;

    const int srow = tid >> 1;            // A-staging: 2 thr/row, 32 ch each
    const int scg  = tid & 1;
    const int srow_l = lane >> 3;         // B-staging coords
    const int kch    = (lane & 7) ^ ((lane >> 3) & 7);

    f32x4 acc[4][8] = {};

    for (int k0 = 0; k0 < K; k0 += 64) {
        // B: 32 chunks of 1KB, 8 per wave (linear dest, inv-swizzled source)
#pragma unroll
        for (int r = 0; r < 8; ++r) {
            const int c = (wid << 3) + r;
            const int row = (c << 3) + srow_l;
            gload16(Bt + (size_t)row * K + k0 + kch * 8,
                    (char*)Bs + (c << 10));
        }
        // A: 32 contiguous f32 ch -> f16, swizzled ds_write_b128
        {
            const float* p = A + (size_t)(m0 + srow) * K + k0 + scg * 32;
            float v[32];
#pragma unroll
            for (int j = 0; j < 8; ++j) {
                float4 a = ((const float4*)p)[j];
                v[j * 4 + 0] = a.x; v[j * 4 + 1] = a.y;
                v[j * 4 + 2] = a.z; v[j * 4 + 3] = a.w;
            }
#pragma unroll
            for (int j = 0; j < 4; ++j) {
                f16x8 hh;
#pragma unroll
                for (int t2 = 0; t2 < 8; ++t2) hh[t2] = (f16)v[j * 8 + t2];
                const int sphys = (scg * 4 + j) ^ (srow & 7);
                *(f16x8*)((char*)As + srow * 128 + sphys * 16) = hh;
            }
        }
        __syncthreads();

#pragma unroll
        for (int h = 0; h < 2; ++h) {
            f16x8 aF[4];
#pragma unroll
            for (int m = 0; m < 4; ++m) {
                const int row  = wr * 64 + m * 16 + (lane & 15);
                const int kg   = (h << 2) + (lane >> 4);
                const int slot = kg ^ (row & 7);
                aF[m] = *(const f16x8*)((const char*)As + row * 128 + slot * 16);
            }
#pragma unroll
            for (int n = 0; n < 8; ++n) {
                const int row  = wc * 128 + n * 16 + (lane & 15);
                const int kg   = (h << 2) + (lane >> 4);
                const int slot = kg ^ (row & 7);
                f16x8 bF = *(const f16x8*)((const char*)Bs + row * 128 + slot * 16);
#pragma unroll
                for (int m = 0; m < 4; ++m)
                    acc[m][n] = __builtin_amdgcn_mfma_f32_16x16x32_f16(
                        aF[m], bF, acc[m][n], 0, 0, 0);
            }
        }
        __syncthreads();
    }

    // linear f16 store (no bias/relu here)
#pragma unroll
    for (int m = 0; m < 4; ++m) {
#pragma unroll
        for (int n = 0; n < 8; ++n) {
            const int col = wc * 128 + n * 16 + (lane & 15);
#pragma unroll
            for (int r = 0; r < 4; ++r) {
                const int row = m0 + wr * 64 + m * 16 + ((lane >> 4) << 2) + r;
                C[(size_t)row * 256 + col] = (f16)acc[m][n][r];
            }
        }
    }
}

// ---------------- k3: h1 = relu(h1pre + sum w_j * y[g_j] + b1), f16 ----------------
// 4 rows per 256-thr block, wave per row, lane handles 4 channels (8B).
__global__ __launch_bounds__(256) void gather_add_relu_kernel(
    const f16* __restrict__ h1pre, const f16* __restrict__ y,
    const int* __restrict__ idx3, const float* __restrict__ w3,
    const float* __restrict__ b1, f16* __restrict__ h1)
{
    const int w = threadIdx.x >> 6, l = threadIdx.x & 63;
    const int m = blockIdx.x * 4 + w;
    const int i0 = idx3[m * 3 + 0], i1 = idx3[m * 3 + 1], i2 = idx3[m * 3 + 2];
    const float w0 = w3[m * 3 + 0], w1 = w3[m * 3 + 1], w2 = w3[m * 3 + 2];
    const int c = l * 4;

    f16x4 hp = *(const f16x4*)&h1pre[(size_t)m * 256 + c];
    f16x4 y0 = *(const f16x4*)&y[(size_t)i0 * 256 + c];
    f16x4 y1 = *(const f16x4*)&y[(size_t)i1 * 256 + c];
    f16x4 y2 = *(const f16x4*)&y[(size_t)i2 * 256 + c];
    float4 bv = *(const float4*)&b1[c];

    f16x4 o;
    o.x = (f16)fmaxf((float)hp.x + w0 * (float)y0.x + w1 * (float)y1.x + w2 * (float)y2.x + bv.x, 0.0f);
    o.y = (f16)fmaxf((float)hp.y + w0 * (float)y0.y + w1 * (float)y1.y + w2 * (float)y2.y + bv.y, 0.0f);
    o.z = (f16)fmaxf((float)hp.z + w0 * (float)y0.z + w1 * (float)y1.z + w2 * (float)y2.z + bv.z, 0.0f);
    o.w = (f16)fmaxf((float)hp.w + w0 * (float)y0.w + w1 * (float)y1.w + w2 * (float)y2.w + bv.w, 0.0f);
    *(f16x4*)&h1[(size_t)m * 256 + c] = o;
}

// ---------------- layer-2 MFMA GEMM: out = relu(h1 @ W2T^T + b2), f32 out ----------------
template <int K>
__global__ __launch_bounds__(256) void gemm_f16_mfma(
    const f16* __restrict__ A, const f16* __restrict__ Bt,
    const float* __restrict__ bias, float* __restrict__ Cout)
{
    __shared__ f16 As[128 * 64];   // 16 KB
    __shared__ f16 Bs[128 * 64];   // 16 KB
    const int tid  = threadIdx.x;
    const int lane = tid & 63;
    const int wid  = tid >> 6;
    const int wr   = wid >> 1, wc = wid & 1;
    const int m0 = blockIdx.x * 128;
    const int n0 = blockIdx.y * 128;

    const int srow_l = lane >> 3;
    const int kch    = (lane & 7) ^ ((lane >> 3) & 7);

    f32x4 acc[4][4] = {};

    for (int k0 = 0; k0 < K; k0 += 64) {
#pragma unroll
        for (int r = 0; r < 4; ++r) {
            const int c = (wid << 2) + r;
            const int row = (c << 3) + srow_l;
            gload16(A  + (size_t)(m0 + row) * K + k0 + kch * 8,
                    (char*)As + (c << 10));
            gload16(Bt + (size_t)(n0 + row) * K + k0 + kch * 8,
                    (char*)Bs + (c << 10));
        }
        __syncthreads();

#pragma unroll
        for (int h = 0; h < 2; ++h) {
            f16x8 aF[4], bF[4];
#pragma unroll
            for (int m = 0; m < 4; ++m) {
                const int row  = wr * 64 + m * 16 + (lane & 15);
                const int kg   = (h << 2) + (lane >> 4);
                const int slot = kg ^ (row & 7);
                aF[m] = *(const f16x8*)((const char*)As + row * 128 + slot * 16);
            }
#pragma unroll
            for (int n = 0; n < 4; ++n) {
                const int row  = wc * 64 + n * 16 + (lane & 15);
                const int kg   = (h << 2) + (lane >> 4);
                const int slot = kg ^ (row & 7);
                bF[n] = *(const f16x8*)((const char*)Bs + row * 128 + slot * 16);
            }
#pragma unroll
            for (int m = 0; m < 4; ++m)
#pragma unroll
                for (int n = 0; n < 4; ++n)
                    acc[m][n] = __builtin_amdgcn_mfma_f32_16x16x32_f16(
                        aF[m], bF[n], acc[m][n], 0, 0, 0);
        }
        __syncthreads();
    }

#pragma unroll
    for (int m = 0; m < 4; ++m) {
#pragma unroll
        for (int n = 0; n < 4; ++n) {
            const int col = n0 + wc * 64 + n * 16 + (lane & 15);
            const float bv = bias[col];
#pragma unroll
            for (int r = 0; r < 4; ++r) {
                const int row = m0 + wr * 64 + m * 16 + ((lane >> 4) << 2) + r;
                Cout[(size_t)row * 256 + col] = fmaxf(acc[m][n][r] + bv, 0.0f);
            }
        }
    }
}

// ---------------- tail: pos_skip passthrough + batch_skip as float ----------------
__global__ __launch_bounds__(256) void copy_tail_kernel(
    const float* __restrict__ pos_skip, const int* __restrict__ batch_skip,
    float* __restrict__ out)
{
    const int i = blockIdx.x * 256 + threadIdx.x;
    const int npos = MTOT * 3;
    if (i < npos)               out[i] = pos_skip[i];
    else if (i < npos + MTOT)   out[i] = (float)batch_skip[i - npos];
}

extern "C" void kernel_launch(void* const* d_in, const int* in_sizes, int n_in,
                              void* d_out, int out_size, void* d_ws, size_t ws_size,
                              hipStream_t stream)
{
    const float* x        = (const float*)d_in[0];
    const float* pos      = (const float*)d_in[1];
    const float* x_skip   = (const float*)d_in[2];
    const float* pos_skip = (const float*)d_in[3];
    const float* W1       = (const float*)d_in[4];
    const float* b1       = (const float*)d_in[5];
    const float* W2       = (const float*)d_in[6];
    const float* b2       = (const float*)d_in[7];
    const int*   batch_skip = (const int*)d_in[9];
    float* out = (float*)d_out;

    char* ws = (char*)d_ws;
    int*   idx3  = (int*)ws;                                // 768 KB
    float* w3    = (float*)(ws + (1u << 20));               // 768 KB
    f16*   W1aT  = (f16*)(ws + (2u << 20));                 // 128 KB
    f16*   W1bT  = (f16*)(ws + (2u << 20) + (256u << 10));  // 64 KB
    f16*   W2T   = (f16*)(ws + (2u << 20) + (512u << 10));  // 128 KB
    f16*   y     = (f16*)(ws + (4u << 20));                 // 8 MB
    f16*   h1pre = (f16*)(ws + (16u << 20));                // 32 MB
    f16*   h1    = (f16*)(ws + (48u << 20));                // 32 MB

    knn_kernel<<<MTOT / 64, 256, 0, stream>>>(pos, pos_skip, idx3, w3);
    wconv_kernel<<<640, 256, 0, stream>>>(W1, W2, W1aT, W1bT, W2T);

    // y = x @ W1a   (M=16384, K=256)
    gemm_regA<256><<<B_ * NC / 128, 256, 0, stream>>>(x, W1aT, y);
    // h1pre = x_skip @ W1b   (M=65536, K=128)
    gemm_regA<128><<<MTOT / 128, 256, 0, stream>>>(x_skip, W1bT, h1pre);
    // h1 = relu(h1pre + gather(y) + b1)
    gather_add_relu_kernel<<<MTOT / 4, 256, 0, stream>>>(h1pre, y, idx3, w3, b1, h1);

    dim3 g2(MTOT / 128, 2);
    gemm_f16_mfma<256><<<g2, 256, 0, stream>>>(h1, W2T, b2, out);

    copy_tail_kernel<<<1024, 256, 0, stream>>>(pos_skip, batch_skip,
                                               out + (size_t)MTOT * CHID);
}

// Round 8
// 216.069 us; speedup vs baseline: 1.2040x; 1.0135x over previous
//
#include <hip/hip_runtime.h>

#define B_ 16
#define NC 1024
#define NF 4096
#define CIN 256
#define CSKIP 128
#define CHID 256
#define MTOT (B_ * NF)   // 65536
#define EPS_ 1e-16f

typedef _Float16 f16;
typedef __attribute__((ext_vector_type(8))) _Float16 f16x8;
typedef __attribute__((ext_vector_type(4))) _Float16 f16x4;
typedef __attribute__((ext_vector_type(2))) _Float16 f16x2;
typedef __attribute__((ext_vector_type(4))) float f32x4;

// K-permutation: stored j holds logical k(j) = (j&~63) + (j&3)*16 + ((j>>2)&15).
// y, h1pre, h1 are all stored in this permuted column space; W2T rows and b1
// are permuted to match, so the math is exact (GEMM invariant under shared
// K-permutation).

// ---------------- kNN top-3, coarse dim split 4x for occupancy ----------------
__global__ __launch_bounds__(256) void knn_kernel(
    const float* __restrict__ pos, const float* __restrict__ pos_skip,
    int* __restrict__ idx3, float* __restrict__ w3)
{
    __shared__ float4 cpos[NC];          // 16 KB
    __shared__ float  cd[64 * 12];       // 3 KB
    __shared__ int    ci[64 * 12];       // 3 KB

    const int b  = blockIdx.x >> 6;
    const int fb = blockIdx.x & 63;
    const float* cp = pos + (size_t)b * NC * 3;
    for (int i = threadIdx.x; i < NC; i += 256)
        cpos[i] = make_float4(cp[i * 3], cp[i * 3 + 1], cp[i * 3 + 2], 0.0f);
    __syncthreads();

    const int fl = threadIdx.x & 63;
    const int q  = threadIdx.x >> 6;
    const int f  = b * NF + fb * 64 + fl;
    const float px = pos_skip[f * 3 + 0];
    const float py = pos_skip[f * 3 + 1];
    const float pz = pos_skip[f * 3 + 2];

    float d0 = 3.4e38f, d1 = 3.4e38f, d2 = 3.4e38f;
    int   i0 = 0, i1 = 0, i2 = 0;
    const int jbase = q << 8;
#pragma unroll 4
    for (int jj = 0; jj < 256; ++jj) {
        const int j = jbase + jj;
        float4 c = cpos[j];
        float dx = px - c.x, dy = py - c.y, dz = pz - c.z;
        float d = fmaf(dx, dx, fmaf(dy, dy, dz * dz));
        if (d < d2) {
            if (d < d1) {
                d2 = d1; i2 = i1;
                if (d < d0) { d1 = d0; i1 = i0; d0 = d; i0 = j; }
                else        { d1 = d;  i1 = j; }
            } else { d2 = d; i2 = j; }
        }
    }
    const int cb = fl * 12 + q * 3;
    cd[cb + 0] = d0; cd[cb + 1] = d1; cd[cb + 2] = d2;
    ci[cb + 0] = i0; ci[cb + 1] = i1; ci[cb + 2] = i2;
    __syncthreads();

    // quarters merged in ascending-index order, strict < insert == top_k ties
    if (threadIdx.x < 64) {
        float e0 = 3.4e38f, e1 = 3.4e38f, e2 = 3.4e38f;
        int   j0 = 0, j1 = 0, j2 = 0;
#pragma unroll
        for (int s = 0; s < 12; ++s) {
            const float d = cd[fl * 12 + s];
            const int   j = ci[fl * 12 + s];
            if (d < e2) {
                if (d < e1) {
                    e2 = e1; j2 = j1;
                    if (d < e0) { e1 = e0; j1 = j0; e0 = d; j0 = j; }
                    else        { e1 = d;  j1 = j; }
                } else { e2 = d; j2 = j; }
            }
        }
        float w0 = 1.0f / fmaxf(e0, EPS_);
        float w1 = 1.0f / fmaxf(e1, EPS_);
        float w2 = 1.0f / fmaxf(e2, EPS_);
        float inv = 1.0f / (w0 + w1 + w2);
        idx3[f * 3 + 0] = b * NC + j0;
        idx3[f * 3 + 1] = b * NC + j1;
        idx3[f * 3 + 2] = b * NC + j2;
        w3[f * 3 + 0] = w0 * inv;
        w3[f * 3 + 1] = w1 * inv;
        w3[f * 3 + 2] = w2 * inv;
    }
}

// ---------------- weights: W1aT[256][256], W1bT[256][128], W2T_s (K-perm), b1p ----------------
__global__ __launch_bounds__(256) void wconv_kernel(
    const float* __restrict__ W1, const float* __restrict__ W2,
    const float* __restrict__ b1,
    f16* __restrict__ W1aT, f16* __restrict__ W1bT, f16* __restrict__ W2T,
    float* __restrict__ b1p)
{
    const int t = blockIdx.x * 256 + threadIdx.x;
    if (t < 256 * 256) {
        const int k = t >> 8, n = t & 255;
        W1aT[n * 256 + k] = (f16)W1[k * 256 + n];
    } else if (t < 256 * 256 + 128 * 256) {
        const int u = t - 256 * 256;
        const int k = u >> 8, n = u & 255;            // k in [0,128)
        W1bT[n * 128 + k] = (f16)W1[(256 + k) * 256 + n];
    } else if (t < 256 * 256 + 128 * 256 + 256 * 256) {
        const int u = t - 256 * 256 - 128 * 256;
        const int n = u >> 8, j = u & 255;
        const int k = (j & ~63) + ((j & 3) << 4) + ((j >> 2) & 15);
        W2T[n * 256 + j] = (f16)W2[k * 256 + n];
    } else if (t < 256 * 256 + 128 * 256 + 256 * 256 + 256) {
        const int j = t - (256 * 256 + 128 * 256 + 256 * 256);
        const int k = (j & ~63) + ((j & 3) << 4) + ((j >> 2) & 15);
        b1p[j] = b1[k];
    }
}

// ---------------- async global->LDS, 16B per lane, linear dest ----------------
__device__ __forceinline__ void gload16(const void* g, void* l)
{
    __builtin_amdgcn_global_load_lds(
        (const __attribute__((address_space(1))) unsigned int*)g,
        (__attribute__((address_space(3))) unsigned int*)l, 16, 0, 0);
}

// ---------------- GEMM, A f32 reg-staged(+cvt), B f16 gload_lds ----------------
// C_s[M][256] = (A @ Bt^T) stored K-permuted f16 via packed f16x4 epilogue.
// BM=128, BN=256 (full N), BK=64, 4 waves (2x2), wave tile 64x128.
template <int K>
__global__ __launch_bounds__(256, 2) void gemm_regA(
    const float* __restrict__ A, const f16* __restrict__ Bt,
    f16* __restrict__ C)
{
    __shared__ f16 As[128 * 64];   // 16 KB
    __shared__ f16 Bs[256 * 64];   // 32 KB
    const int tid  = threadIdx.x;
    const int lane = tid & 63;
    const int wid  = tid >> 6;
    const int wr   = wid >> 1, wc = wid & 1;
    const int m0   = blockIdx.x * 128;

    const int srow = tid >> 1;            // A-staging: 2 thr/row, 32 ch each
    const int scg  = tid & 1;
    const int srow_l = lane >> 3;         // B-staging coords
    const int kch    = (lane & 7) ^ ((lane >> 3) & 7);

    f32x4 acc[4][8] = {};

    for (int k0 = 0; k0 < K; k0 += 64) {
        // B: 32 chunks of 1KB, 8 per wave (linear dest, inv-swizzled source)
#pragma unroll
        for (int r = 0; r < 8; ++r) {
            const int c = (wid << 3) + r;
            const int row = (c << 3) + srow_l;
            gload16(Bt + (size_t)row * K + k0 + kch * 8,
                    (char*)Bs + (c << 10));
        }
        // A: 32 contiguous f32 ch -> f16, swizzled ds_write_b128
        {
            const float* p = A + (size_t)(m0 + srow) * K + k0 + scg * 32;
            float v[32];
#pragma unroll
            for (int j = 0; j < 8; ++j) {
                float4 a = ((const float4*)p)[j];
                v[j * 4 + 0] = a.x; v[j * 4 + 1] = a.y;
                v[j * 4 + 2] = a.z; v[j * 4 + 3] = a.w;
            }
#pragma unroll
            for (int j = 0; j < 4; ++j) {
                f16x8 hh;
#pragma unroll
                for (int t2 = 0; t2 < 8; ++t2) hh[t2] = (f16)v[j * 8 + t2];
                const int sphys = (scg * 4 + j) ^ (srow & 7);
                *(f16x8*)((char*)As + srow * 128 + sphys * 16) = hh;
            }
        }
        __syncthreads();

#pragma unroll
        for (int h = 0; h < 2; ++h) {
            f16x8 aF[4];
#pragma unroll
            for (int m = 0; m < 4; ++m) {
                const int row  = wr * 64 + m * 16 + (lane & 15);
                const int kg   = (h << 2) + (lane >> 4);
                const int slot = kg ^ (row & 7);
                aF[m] = *(const f16x8*)((const char*)As + row * 128 + slot * 16);
            }
#pragma unroll
            for (int n = 0; n < 8; ++n) {
                const int row  = wc * 128 + n * 16 + (lane & 15);
                const int kg   = (h << 2) + (lane >> 4);
                const int slot = kg ^ (row & 7);
                f16x8 bF = *(const f16x8*)((const char*)Bs + row * 128 + slot * 16);
#pragma unroll
                for (int m = 0; m < 4; ++m)
                    acc[m][n] = __builtin_amdgcn_mfma_f32_16x16x32_f16(
                        aF[m], bF, acc[m][n], 0, 0, 0);
            }
        }
        __syncthreads();
    }

    // packed K-permuted store: cols (g*4+n)*16+q -> stored j = g*64 + q*4 + n
    const int qq = lane & 15;
#pragma unroll
    for (int m = 0; m < 4; ++m) {
        const int rb = wr * 64 + m * 16 + ((lane >> 4) << 2);
#pragma unroll
        for (int r = 0; r < 4; ++r) {
            const int rg = m0 + rb + r;
#pragma unroll
            for (int g = 0; g < 2; ++g) {
                f16x4 hv;
#pragma unroll
                for (int n = 0; n < 4; ++n)
                    hv[n] = (f16)acc[m][g * 4 + n][r];
                *(f16x4*)&C[(size_t)rg * 256 + wc * 128 + g * 64 + qq * 4] = hv;
            }
        }
    }
}

// ---------------- k3: h1 = relu(h1pre + sum w_j * y[g_j] + b1p), permuted space ----------------
__global__ __launch_bounds__(256) void gather_add_relu_kernel(
    const f16* __restrict__ h1pre, const f16* __restrict__ y,
    const int* __restrict__ idx3, const float* __restrict__ w3,
    const float* __restrict__ b1p, f16* __restrict__ h1)
{
    const int w = threadIdx.x >> 6, l = threadIdx.x & 63;
    const int m = blockIdx.x * 4 + w;
    const int i0 = idx3[m * 3 + 0], i1 = idx3[m * 3 + 1], i2 = idx3[m * 3 + 2];
    const float w0 = w3[m * 3 + 0], w1 = w3[m * 3 + 1], w2 = w3[m * 3 + 2];
    const int c = l * 4;

    f16x4 hp = *(const f16x4*)&h1pre[(size_t)m * 256 + c];
    f16x4 y0 = *(const f16x4*)&y[(size_t)i0 * 256 + c];
    f16x4 y1 = *(const f16x4*)&y[(size_t)i1 * 256 + c];
    f16x4 y2 = *(const f16x4*)&y[(size_t)i2 * 256 + c];
    float4 bv = *(const float4*)&b1p[c];

    f16x4 o;
    o.x = (f16)fmaxf((float)hp.x + w0 * (float)y0.x + w1 * (float)y1.x + w2 * (float)y2.x + bv.x, 0.0f);
    o.y = (f16)fmaxf((float)hp.y + w0 * (float)y0.y + w1 * (float)y1.y + w2 * (float)y2.y + bv.y, 0.0f);
    o.z = (f16)fmaxf((float)hp.z + w0 * (float)y0.z + w1 * (float)y1.z + w2 * (float)y2.z + bv.z, 0.0f);
    o.w = (f16)fmaxf((float)hp.w + w0 * (float)y0.w + w1 * (float)y1.w + w2 * (float)y2.w + bv.w, 0.0f);
    *(f16x4*)&h1[(size_t)m * 256 + c] = o;
}

// ---------------- layer-2 GEMM: out = relu(h1_s @ W2T_s^T + b2), f32 standard layout ----------------
// BM=128, BN=256 (full N), BK=64; A (h1_s) f16 via gload_lds, 4 chunks/wave.
__global__ __launch_bounds__(256, 2) void gemm2_kernel(
    const f16* __restrict__ A, const f16* __restrict__ Bt,
    const float* __restrict__ bias, float* __restrict__ out)
{
    __shared__ f16 As[128 * 64];   // 16 KB
    __shared__ f16 Bs[256 * 64];   // 32 KB
    const int tid  = threadIdx.x;
    const int lane = tid & 63;
    const int wid  = tid >> 6;
    const int wr   = wid >> 1, wc = wid & 1;
    const int m0   = blockIdx.x * 128;

    const int srow_l = lane >> 3;
    const int kch    = (lane & 7) ^ ((lane >> 3) & 7);

    f32x4 acc[4][8] = {};

    for (int k0 = 0; k0 < 256; k0 += 64) {
#pragma unroll
        for (int r = 0; r < 4; ++r) {           // A: 16 chunks, 4 per wave
            const int c = (wid << 2) + r;
            const int row = (c << 3) + srow_l;
            gload16(A + (size_t)(m0 + row) * 256 + k0 + kch * 8,
                    (char*)As + (c << 10));
        }
#pragma unroll
        for (int r = 0; r < 8; ++r) {           // B: 32 chunks, 8 per wave
            const int c = (wid << 3) + r;
            const int row = (c << 3) + srow_l;
            gload16(Bt + (size_t)row * 256 + k0 + kch * 8,
                    (char*)Bs + (c << 10));
        }
        __syncthreads();

#pragma unroll
        for (int h = 0; h < 2; ++h) {
            f16x8 aF[4];
#pragma unroll
            for (int m = 0; m < 4; ++m) {
                const int row  = wr * 64 + m * 16 + (lane & 15);
                const int kg   = (h << 2) + (lane >> 4);
                const int slot = kg ^ (row & 7);
                aF[m] = *(const f16x8*)((const char*)As + row * 128 + slot * 16);
            }
#pragma unroll
            for (int n = 0; n < 8; ++n) {
                const int row  = wc * 128 + n * 16 + (lane & 15);
                const int kg   = (h << 2) + (lane >> 4);
                const int slot = kg ^ (row & 7);
                f16x8 bF = *(const f16x8*)((const char*)Bs + row * 128 + slot * 16);
#pragma unroll
                for (int m = 0; m < 4; ++m)
                    acc[m][n] = __builtin_amdgcn_mfma_f32_16x16x32_f16(
                        aF[m], bF, acc[m][n], 0, 0, 0);
            }
        }
        __syncthreads();
    }

    // standard-layout f32 store + bias + relu
#pragma unroll
    for (int m = 0; m < 4; ++m) {
#pragma unroll
        for (int n = 0; n < 8; ++n) {
            const int col = wc * 128 + n * 16 + (lane & 15);
            const float bv = bias[col];
#pragma unroll
            for (int r = 0; r < 4; ++r) {
                const int row = m0 + wr * 64 + m * 16 + ((lane >> 4) << 2) + r;
                out[(size_t)row * 256 + col] = fmaxf(acc[m][n][r] + bv, 0.0f);
            }
        }
    }
}

// ---------------- tail: pos_skip passthrough + batch_skip as float ----------------
__global__ __launch_bounds__(256) void copy_tail_kernel(
    const float* __restrict__ pos_skip, const int* __restrict__ batch_skip,
    float* __restrict__ out)
{
    const int i = blockIdx.x * 256 + threadIdx.x;
    const int npos = MTOT * 3;
    if (i < npos)               out[i] = pos_skip[i];
    else if (i < npos + MTOT)   out[i] = (float)batch_skip[i - npos];
}

extern "C" void kernel_launch(void* const* d_in, const int* in_sizes, int n_in,
                              void* d_out, int out_size, void* d_ws, size_t ws_size,
                              hipStream_t stream)
{
    const float* x        = (const float*)d_in[0];
    const float* pos      = (const float*)d_in[1];
    const float* x_skip   = (const float*)d_in[2];
    const float* pos_skip = (const float*)d_in[3];
    const float* W1       = (const float*)d_in[4];
    const float* b1       = (const float*)d_in[5];
    const float* W2       = (const float*)d_in[6];
    const float* b2       = (const float*)d_in[7];
    const int*   batch_skip = (const int*)d_in[9];
    float* out = (float*)d_out;

    char* ws = (char*)d_ws;
    int*   idx3  = (int*)ws;                                // 768 KB
    float* w3    = (float*)(ws + (1u << 20));               // 768 KB
    f16*   W1aT  = (f16*)(ws + (2u << 20));                 // 128 KB
    f16*   W1bT  = (f16*)(ws + (2u << 20) + (256u << 10));  // 64 KB
    f16*   W2T   = (f16*)(ws + (2u << 20) + (512u << 10));  // 128 KB
    float* b1p   = (float*)(ws + (2u << 20) + (768u << 10)); // 1 KB
    f16*   y     = (f16*)(ws + (4u << 20));                 // 8 MB
    f16*   h1pre = (f16*)(ws + (16u << 20));                // 32 MB
    f16*   h1    = (f16*)(ws + (48u << 20));                // 32 MB

    knn_kernel<<<MTOT / 64, 256, 0, stream>>>(pos, pos_skip, idx3, w3);
    wconv_kernel<<<641, 256, 0, stream>>>(W1, W2, b1, W1aT, W1bT, W2T, b1p);

    // y = x @ W1a   (M=16384, K=256), K-permuted store
    gemm_regA<256><<<B_ * NC / 128, 256, 0, stream>>>(x, W1aT, y);
    // h1pre = x_skip @ W1b   (M=65536, K=128), K-permuted store
    gemm_regA<128><<<MTOT / 128, 256, 0, stream>>>(x_skip, W1bT, h1pre);
    // h1 = relu(h1pre + gather(y) + b1p)   (elementwise in permuted space)
    gather_add_relu_kernel<<<MTOT / 4, 256, 0, stream>>>(h1pre, y, idx3, w3, b1p, h1);

    // out = relu(h1 @ W2T^T + b2)  (permutation cancels)
    gemm2_kernel<<<MTOT / 128, 256, 0, stream>>>(h1, W2T, b2, out);

    copy_tail_kernel<<<1024, 256, 0, stream>>>(pos_skip, batch_skip,
                                               out + (size_t)MTOT * CHID);
}

// Round 9
// 199.049 us; speedup vs baseline: 1.3070x; 1.0855x over previous
//
#include <hip/hip_runtime.h>

#define B_ 16
#define NC 1024
#define NF 4096
#define CIN 256
#define CSKIP 128
#define CHID 256
#define MTOT (B_ * NF)   // 65536
#define EPS_ 1e-16f

typedef _Float16 f16;
typedef __attribute__((ext_vector_type(8))) _Float16 f16x8;
typedef __attribute__((ext_vector_type(4))) _Float16 f16x4;
typedef __attribute__((ext_vector_type(4))) float f32x4;

// K-permutation: stored j holds logical k(j) = (j&~63) + (j&3)*16 + ((j>>2)&15).
// y and h1 live in this permuted column space; W2T rows and b1p are permuted
// to match, so gemm2 cancels the permutation exactly.

// ---------------- misc: knn (blocks 0..1023) + wconv (1024..1664) + tail (1665..2688) ----------------
__global__ __launch_bounds__(256) void misc_kernel(
    const float* __restrict__ pos, const float* __restrict__ pos_skip,
    const int* __restrict__ batch_skip,
    const float* __restrict__ W1, const float* __restrict__ W2,
    const float* __restrict__ b1,
    int* __restrict__ idx3, float* __restrict__ w3,
    f16* __restrict__ W1aT, f16* __restrict__ W1bT, f16* __restrict__ W2T,
    float* __restrict__ b1p, float* __restrict__ out_tail)
{
    __shared__ float4 cpos[NC];          // 16 KB (knn branch only)
    __shared__ float  cd[64 * 12];
    __shared__ int    ci[64 * 12];

    const int bid = blockIdx.x;
    if (bid < 1024) {
        // ---- kNN top-3, coarse dim split 4x ----
        const int b  = bid >> 6;
        const int fb = bid & 63;
        const float* cp = pos + (size_t)b * NC * 3;
        for (int i = threadIdx.x; i < NC; i += 256)
            cpos[i] = make_float4(cp[i * 3], cp[i * 3 + 1], cp[i * 3 + 2], 0.0f);
        __syncthreads();

        const int fl = threadIdx.x & 63;
        const int q  = threadIdx.x >> 6;
        const int f  = b * NF + fb * 64 + fl;
        const float px = pos_skip[f * 3 + 0];
        const float py = pos_skip[f * 3 + 1];
        const float pz = pos_skip[f * 3 + 2];

        float d0 = 3.4e38f, d1 = 3.4e38f, d2 = 3.4e38f;
        int   i0 = 0, i1 = 0, i2 = 0;
        const int jbase = q << 8;
#pragma unroll 4
        for (int jj = 0; jj < 256; ++jj) {
            const int j = jbase + jj;
            float4 c = cpos[j];
            float dx = px - c.x, dy = py - c.y, dz = pz - c.z;
            float d = fmaf(dx, dx, fmaf(dy, dy, dz * dz));
            if (d < d2) {
                if (d < d1) {
                    d2 = d1; i2 = i1;
                    if (d < d0) { d1 = d0; i1 = i0; d0 = d; i0 = j; }
                    else        { d1 = d;  i1 = j; }
                } else { d2 = d; i2 = j; }
            }
        }
        const int cb = fl * 12 + q * 3;
        cd[cb + 0] = d0; cd[cb + 1] = d1; cd[cb + 2] = d2;
        ci[cb + 0] = i0; ci[cb + 1] = i1; ci[cb + 2] = i2;
        __syncthreads();

        // quarters merged ascending-index, strict < insert == top_k tie rule
        if (threadIdx.x < 64) {
            float e0 = 3.4e38f, e1 = 3.4e38f, e2 = 3.4e38f;
            int   j0 = 0, j1 = 0, j2 = 0;
#pragma unroll
            for (int s = 0; s < 12; ++s) {
                const float d = cd[fl * 12 + s];
                const int   j = ci[fl * 12 + s];
                if (d < e2) {
                    if (d < e1) {
                        e2 = e1; j2 = j1;
                        if (d < e0) { e1 = e0; j1 = j0; e0 = d; j0 = j; }
                        else        { e1 = d;  j1 = j; }
                    } else { e2 = d; j2 = j; }
                }
            }
            float w0 = 1.0f / fmaxf(e0, EPS_);
            float w1 = 1.0f / fmaxf(e1, EPS_);
            float w2 = 1.0f / fmaxf(e2, EPS_);
            float inv = 1.0f / (w0 + w1 + w2);
            idx3[f * 3 + 0] = b * NC + j0;
            idx3[f * 3 + 1] = b * NC + j1;
            idx3[f * 3 + 2] = b * NC + j2;
            w3[f * 3 + 0] = w0 * inv;
            w3[f * 3 + 1] = w1 * inv;
            w3[f * 3 + 2] = w2 * inv;
        }
    } else if (bid < 1665) {
        // ---- weight convert/transpose + b1 permute ----
        const int t = (bid - 1024) * 256 + threadIdx.x;
        if (t < 256 * 256) {
            const int k = t >> 8, n = t & 255;
            W1aT[n * 256 + k] = (f16)W1[k * 256 + n];
        } else if (t < 256 * 256 + 128 * 256) {
            const int u = t - 256 * 256;
            const int k = u >> 8, n = u & 255;
            W1bT[n * 128 + k] = (f16)W1[(256 + k) * 256 + n];
        } else if (t < 256 * 256 + 128 * 256 + 256 * 256) {
            const int u = t - 256 * 256 - 128 * 256;
            const int n = u >> 8, j = u & 255;
            const int k = (j & ~63) + ((j & 3) << 4) + ((j >> 2) & 15);
            W2T[n * 256 + j] = (f16)W2[k * 256 + n];
        } else if (t < 256 * 256 + 128 * 256 + 256 * 256 + 256) {
            const int j = t - (256 * 256 + 128 * 256 + 256 * 256);
            const int k = (j & ~63) + ((j & 3) << 4) + ((j >> 2) & 15);
            b1p[j] = b1[k];
        }
    } else {
        // ---- tail: pos_skip passthrough + batch_skip as float ----
        const int i = (bid - 1665) * 256 + threadIdx.x;
        const int npos = MTOT * 3;
        if (i < npos)               out_tail[i] = pos_skip[i];
        else if (i < npos + MTOT)   out_tail[i] = (float)batch_skip[i - npos];
    }
}

// ---------------- async global->LDS, 16B per lane, linear dest ----------------
__device__ __forceinline__ void gload16(const void* g, void* l)
{
    __builtin_amdgcn_global_load_lds(
        (const __attribute__((address_space(1))) unsigned int*)g,
        (__attribute__((address_space(3))) unsigned int*)l, 16, 0, 0);
}

// ---------------- y = x @ W1aT^T, K-permuted f16 store ----------------
// BM=128, BN=256, BK=64, 4 waves (2x2), wave tile 64x128. A f32 reg-staged.
__global__ __launch_bounds__(256, 2) void gemm_y(
    const float* __restrict__ A, const f16* __restrict__ Bt,
    f16* __restrict__ C)
{
    __shared__ f16 As[128 * 64];   // 16 KB
    __shared__ f16 Bs[256 * 64];   // 32 KB
    const int tid  = threadIdx.x;
    const int lane = tid & 63;
    const int wid  = tid >> 6;
    const int wr   = wid >> 1, wc = wid & 1;
    const int m0   = blockIdx.x * 128;

    const int srow = tid >> 1;
    const int scg  = tid & 1;
    const int srow_l = lane >> 3;
    const int kch    = (lane & 7) ^ ((lane >> 3) & 7);

    f32x4 acc[4][8] = {};

    for (int k0 = 0; k0 < 256; k0 += 64) {
#pragma unroll
        for (int r = 0; r < 8; ++r) {
            const int c = (wid << 3) + r;
            const int row = (c << 3) + srow_l;
            gload16(Bt + (size_t)row * 256 + k0 + kch * 8,
                    (char*)Bs + (c << 10));
        }
        {
            const float* p = A + (size_t)(m0 + srow) * 256 + k0 + scg * 32;
            float v[32];
#pragma unroll
            for (int j = 0; j < 8; ++j) {
                float4 a = ((const float4*)p)[j];
                v[j * 4 + 0] = a.x; v[j * 4 + 1] = a.y;
                v[j * 4 + 2] = a.z; v[j * 4 + 3] = a.w;
            }
#pragma unroll
            for (int j = 0; j < 4; ++j) {
                f16x8 hh;
#pragma unroll
                for (int t2 = 0; t2 < 8; ++t2) hh[t2] = (f16)v[j * 8 + t2];
                const int sphys = (scg * 4 + j) ^ (srow & 7);
                *(f16x8*)((char*)As + srow * 128 + sphys * 16) = hh;
            }
        }
        __syncthreads();

#pragma unroll
        for (int h = 0; h < 2; ++h) {
            f16x8 aF[4];
#pragma unroll
            for (int m = 0; m < 4; ++m) {
                const int row  = wr * 64 + m * 16 + (lane & 15);
                const int kg   = (h << 2) + (lane >> 4);
                const int slot = kg ^ (row & 7);
                aF[m] = *(const f16x8*)((const char*)As + row * 128 + slot * 16);
            }
#pragma unroll
            for (int n = 0; n < 8; ++n) {
                const int row  = wc * 128 + n * 16 + (lane & 15);
                const int kg   = (h << 2) + (lane >> 4);
                const int slot = kg ^ (row & 7);
                f16x8 bF = *(const f16x8*)((const char*)Bs + row * 128 + slot * 16);
#pragma unroll
                for (int m = 0; m < 4; ++m)
                    acc[m][n] = __builtin_amdgcn_mfma_f32_16x16x32_f16(
                        aF[m], bF, acc[m][n], 0, 0, 0);
            }
        }
        __syncthreads();
    }

    // packed K-permuted store: cols (g*4+n)*16+q -> stored j = g*64 + q*4 + n
    const int qq = lane & 15;
#pragma unroll
    for (int m = 0; m < 4; ++m) {
        const int rb = wr * 64 + m * 16 + ((lane >> 4) << 2);
#pragma unroll
        for (int r = 0; r < 4; ++r) {
            const int rg = m0 + rb + r;
#pragma unroll
            for (int g = 0; g < 2; ++g) {
                f16x4 hv;
#pragma unroll
                for (int n = 0; n < 4; ++n)
                    hv[n] = (f16)acc[m][g * 4 + n][r];
                *(f16x4*)&C[(size_t)rg * 256 + wc * 128 + g * 64 + qq * 4] = hv;
            }
        }
    }
}

// ---------------- fused layer-1b: h1 = relu(x_skip@W1bT + gather(y) + b1p) ----------------
// Same GEMM body (K=128); gather+bias+relu fused into the (barrier-free)
// epilogue: per output row, 3 L2-warm y-row reads; acc stays f32 until after
// the add. Eliminates the 64 MB h1pre round-trip + one launch.
__global__ __launch_bounds__(256, 2) void gemm1b_fused(
    const float* __restrict__ A, const f16* __restrict__ Bt,
    const f16* __restrict__ y,
    const int* __restrict__ idx3, const float* __restrict__ w3,
    const float* __restrict__ b1p, f16* __restrict__ h1)
{
    __shared__ f16 As[128 * 64];   // 16 KB
    __shared__ f16 Bs[256 * 64];   // 32 KB
    const int tid  = threadIdx.x;
    const int lane = tid & 63;
    const int wid  = tid >> 6;
    const int wr   = wid >> 1, wc = wid & 1;
    const int m0   = blockIdx.x * 128;

    const int srow = tid >> 1;
    const int scg  = tid & 1;
    const int srow_l = lane >> 3;
    const int kch    = (lane & 7) ^ ((lane >> 3) & 7);

    f32x4 acc[4][8] = {};

    for (int k0 = 0; k0 < 128; k0 += 64) {
#pragma unroll
        for (int r = 0; r < 8; ++r) {
            const int c = (wid << 3) + r;
            const int row = (c << 3) + srow_l;
            gload16(Bt + (size_t)row * 128 + k0 + kch * 8,
                    (char*)Bs + (c << 10));
        }
        {
            const float* p = A + (size_t)(m0 + srow) * 128 + k0 + scg * 32;
            float v[32];
#pragma unroll
            for (int j = 0; j < 8; ++j) {
                float4 a = ((const float4*)p)[j];
                v[j * 4 + 0] = a.x; v[j * 4 + 1] = a.y;
                v[j * 4 + 2] = a.z; v[j * 4 + 3] = a.w;
            }
#pragma unroll
            for (int j = 0; j < 4; ++j) {
                f16x8 hh;
#pragma unroll
                for (int t2 = 0; t2 < 8; ++t2) hh[t2] = (f16)v[j * 8 + t2];
                const int sphys = (scg * 4 + j) ^ (srow & 7);
                *(f16x8*)((char*)As + srow * 128 + sphys * 16) = hh;
            }
        }
        __syncthreads();

#pragma unroll
        for (int h = 0; h < 2; ++h) {
            f16x8 aF[4];
#pragma unroll
            for (int m = 0; m < 4; ++m) {
                const int row  = wr * 64 + m * 16 + (lane & 15);
                const int kg   = (h << 2) + (lane >> 4);
                const int slot = kg ^ (row & 7);
                aF[m] = *(const f16x8*)((const char*)As + row * 128 + slot * 16);
            }
#pragma unroll
            for (int n = 0; n < 8; ++n) {
                const int row  = wc * 128 + n * 16 + (lane & 15);
                const int kg   = (h << 2) + (lane >> 4);
                const int slot = kg ^ (row & 7);
                f16x8 bF = *(const f16x8*)((const char*)Bs + row * 128 + slot * 16);
#pragma unroll
                for (int m = 0; m < 4; ++m)
                    acc[m][n] = __builtin_amdgcn_mfma_f32_16x16x32_f16(
                        aF[m], bF, acc[m][n], 0, 0, 0);
            }
        }
        __syncthreads();
    }

    // fused epilogue: h1 = relu(acc + sum w_j*y[g_j] + b1p), permuted cols
    const int qq = lane & 15;
    const f32x4 bv0 = *(const f32x4*)&b1p[wc * 128 + qq * 4];
    const f32x4 bv1 = *(const f32x4*)&b1p[wc * 128 + 64 + qq * 4];
#pragma unroll
    for (int m = 0; m < 4; ++m) {
        const int rb = wr * 64 + m * 16 + ((lane >> 4) << 2);
#pragma unroll
        for (int r = 0; r < 4; ++r) {
            const int rg = m0 + rb + r;
            const int i0 = idx3[rg * 3 + 0], i1 = idx3[rg * 3 + 1], i2 = idx3[rg * 3 + 2];
            const float w0 = w3[rg * 3 + 0], w1 = w3[rg * 3 + 1], w2 = w3[rg * 3 + 2];
#pragma unroll
            for (int g = 0; g < 2; ++g) {
                const int jb = wc * 128 + g * 64 + qq * 4;
                f16x4 y0 = *(const f16x4*)&y[(size_t)i0 * 256 + jb];
                f16x4 y1 = *(const f16x4*)&y[(size_t)i1 * 256 + jb];
                f16x4 y2 = *(const f16x4*)&y[(size_t)i2 * 256 + jb];
                const f32x4 bv = g ? bv1 : bv0;
                f16x4 hv;
#pragma unroll
                for (int n = 0; n < 4; ++n) {
                    float v = acc[m][g * 4 + n][r]
                            + w0 * (float)y0[n] + w1 * (float)y1[n] + w2 * (float)y2[n]
                            + bv[n];
                    hv[n] = (f16)fmaxf(v, 0.0f);
                }
                *(f16x4*)&h1[(size_t)rg * 256 + jb] = hv;
            }
        }
    }
}

// ---------------- layer-2 GEMM: out = relu(h1_s @ W2T_s^T + b2), f32 standard layout ----------------
__global__ __launch_bounds__(256, 2) void gemm2_kernel(
    const f16* __restrict__ A, const f16* __restrict__ Bt,
    const float* __restrict__ bias, float* __restrict__ out)
{
    __shared__ f16 As[128 * 64];   // 16 KB
    __shared__ f16 Bs[256 * 64];   // 32 KB
    const int tid  = threadIdx.x;
    const int lane = tid & 63;
    const int wid  = tid >> 6;
    const int wr   = wid >> 1, wc = wid & 1;
    const int m0   = blockIdx.x * 128;

    const int srow_l = lane >> 3;
    const int kch    = (lane & 7) ^ ((lane >> 3) & 7);

    f32x4 acc[4][8] = {};

    for (int k0 = 0; k0 < 256; k0 += 64) {
#pragma unroll
        for (int r = 0; r < 4; ++r) {           // A: 16 chunks, 4 per wave
            const int c = (wid << 2) + r;
            const int row = (c << 3) + srow_l;
            gload16(A + (size_t)(m0 + row) * 256 + k0 + kch * 8,
                    (char*)As + (c << 10));
        }
#pragma unroll
        for (int r = 0; r < 8; ++r) {           // B: 32 chunks, 8 per wave
            const int c = (wid << 3) + r;
            const int row = (c << 3) + srow_l;
            gload16(Bt + (size_t)row * 256 + k0 + kch * 8,
                    (char*)Bs + (c << 10));
        }
        __syncthreads();

#pragma unroll
        for (int h = 0; h < 2; ++h) {
            f16x8 aF[4];
#pragma unroll
            for (int m = 0; m < 4; ++m) {
                const int row  = wr * 64 + m * 16 + (lane & 15);
                const int kg   = (h << 2) + (lane >> 4);
                const int slot = kg ^ (row & 7);
                aF[m] = *(const f16x8*)((const char*)As + row * 128 + slot * 16);
            }
#pragma unroll
            for (int n = 0; n < 8; ++n) {
                const int row  = wc * 128 + n * 16 + (lane & 15);
                const int kg   = (h << 2) + (lane >> 4);
                const int slot = kg ^ (row & 7);
                f16x8 bF = *(const f16x8*)((const char*)Bs + row * 128 + slot * 16);
#pragma unroll
                for (int m = 0; m < 4; ++m)
                    acc[m][n] = __builtin_amdgcn_mfma_f32_16x16x32_f16(
                        aF[m], bF, acc[m][n], 0, 0, 0);
            }
        }
        __syncthreads();
    }

    // standard-layout f32 store + bias + relu
#pragma unroll
    for (int m = 0; m < 4; ++m) {
#pragma unroll
        for (int n = 0; n < 8; ++n) {
            const int col = wc * 128 + n * 16 + (lane & 15);
            const float bv = bias[col];
#pragma unroll
            for (int r = 0; r < 4; ++r) {
                const int row = m0 + wr * 64 + m * 16 + ((lane >> 4) << 2) + r;
                out[(size_t)row * 256 + col] = fmaxf(acc[m][n][r] + bv, 0.0f);
            }
        }
    }
}

extern "C" void kernel_launch(void* const* d_in, const int* in_sizes, int n_in,
                              void* d_out, int out_size, void* d_ws, size_t ws_size,
                              hipStream_t stream)
{
    const float* x        = (const float*)d_in[0];
    const float* pos      = (const float*)d_in[1];
    const float* x_skip   = (const float*)d_in[2];
    const float* pos_skip = (const float*)d_in[3];
    const float* W1       = (const float*)d_in[4];
    const float* b1       = (const float*)d_in[5];
    const float* W2       = (const float*)d_in[6];
    const float* b2       = (const float*)d_in[7];
    const int*   batch_skip = (const int*)d_in[9];
    float* out = (float*)d_out;

    char* ws = (char*)d_ws;
    int*   idx3  = (int*)ws;                                 // 768 KB
    float* w3    = (float*)(ws + (1u << 20));                // 768 KB
    f16*   W1aT  = (f16*)(ws + (2u << 20));                  // 128 KB
    f16*   W1bT  = (f16*)(ws + (2u << 20) + (256u << 10));   // 64 KB
    f16*   W2T   = (f16*)(ws + (2u << 20) + (512u << 10));   // 128 KB
    float* b1p   = (float*)(ws + (2u << 20) + (768u << 10)); // 1 KB
    f16*   y     = (f16*)(ws + (4u << 20));                  // 8 MB
    f16*   h1    = (f16*)(ws + (16u << 20));                 // 32 MB

    // knn + weight-convert + output-tail, fused (mutually independent)
    misc_kernel<<<2689, 256, 0, stream>>>(
        pos, pos_skip, batch_skip, W1, W2, b1,
        idx3, w3, W1aT, W1bT, W2T, b1p, out + (size_t)MTOT * CHID);

    // y = x @ W1a   (M=16384, K=256), K-permuted store
    gemm_y<<<B_ * NC / 128, 256, 0, stream>>>(x, W1aT, y);

    // h1 = relu(x_skip @ W1b + gather(y) + b1p)  (epilogue-fused gather)
    gemm1b_fused<<<MTOT / 128, 256, 0, stream>>>(x_skip, W1bT, y, idx3, w3, b1p, h1);

    // out = relu(h1 @ W2T^T + b2)  (permutation cancels)
    gemm2_kernel<<<MTOT / 128, 256, 0, stream>>>(h1, W2T, b2, out);
}

// Round 12
// 198.539 us; speedup vs baseline: 1.3103x; 1.0026x over previous
//
#include <hip/hip_runtime.h>

#define B_ 16
#define NC 1024
#define NF 4096
#define CIN 256
#define CSKIP 128
#define CHID 256
#define MTOT (B_ * NF)   // 65536
#define EPS_ 1e-16f

typedef _Float16 f16;
typedef __attribute__((ext_vector_type(8))) _Float16 f16x8;
typedef __attribute__((ext_vector_type(4))) _Float16 f16x4;
typedef __attribute__((ext_vector_type(4))) float f32x4;

// K-permutation: stored j holds logical k(j) = (j&~63) + (j&3)*16 + ((j>>2)&15).
// y and h1 live in this permuted column space; W2T rows and b1p are permuted
// to match, so gemm2 cancels the permutation exactly.

// ---------------- misc: knn (blocks 0..2047) + wconv (2048..2688) + tail (2689..3712) ----------------
// knn: 32 fine pts x 8 coarse-eighths per 256-thr block (7 blocks/CU, ~88%
// occupancy cap). Exact difference-form d^2 + full-precision (dist,idx)
// insert chain — matches jax.lax.top_k selection/ties (round-10's truncated
// packing broke set selection; reverted).
__global__ __launch_bounds__(256) void misc_kernel(
    const float* __restrict__ pos, const float* __restrict__ pos_skip,
    const int* __restrict__ batch_skip,
    const float* __restrict__ W1, const float* __restrict__ W2,
    const float* __restrict__ b1,
    int* __restrict__ idx3, float* __restrict__ w3,
    f16* __restrict__ W1aT, f16* __restrict__ W1bT, f16* __restrict__ W2T,
    float* __restrict__ b1p, float* __restrict__ out_tail)
{
    __shared__ float4 cpos[NC];        // 16 KB
    __shared__ float  cd[32 * 24];     // 3 KB
    __shared__ int    ci[32 * 24];     // 3 KB

    const int bid = blockIdx.x;
    if (bid < 2048) {
        // ---- kNN top-3 ----
        const int b  = bid >> 7;          // batch (128 blocks per batch)
        const int fb = bid & 127;         // fine 32-group within batch
        const float* cp = pos + (size_t)b * NC * 3;
        for (int i = threadIdx.x; i < NC; i += 256)
            cpos[i] = make_float4(cp[i * 3], cp[i * 3 + 1], cp[i * 3 + 2], 0.0f);
        __syncthreads();

        const int fl = threadIdx.x & 31;
        const int q  = threadIdx.x >> 5;          // eighth 0..7
        const int f  = b * NF + fb * 32 + fl;
        const float px = pos_skip[f * 3 + 0];
        const float py = pos_skip[f * 3 + 1];
        const float pz = pos_skip[f * 3 + 2];

        float d0 = 3.4e38f, d1 = 3.4e38f, d2 = 3.4e38f;
        int   i0 = 0, i1 = 0, i2 = 0;
        const int jbase = q << 7;
#pragma unroll 4
        for (int jj = 0; jj < 128; ++jj) {
            const int j = jbase + jj;
            float4 c = cpos[j];
            float dx = px - c.x, dy = py - c.y, dz = pz - c.z;
            float d = fmaf(dx, dx, fmaf(dy, dy, dz * dz));
            const bool c2 = d < d2, c1 = d < d1, c0 = d < d0;
            d2 = c1 ? d1 : (c2 ? d : d2);  i2 = c1 ? i1 : (c2 ? j : i2);
            d1 = c0 ? d0 : (c1 ? d : d1);  i1 = c0 ? i0 : (c1 ? j : i1);
            d0 = c0 ? d  : d0;             i0 = c0 ? j  : i0;
        }
        const int cb = fl * 24 + q * 3;
        cd[cb + 0] = d0; cd[cb + 1] = d1; cd[cb + 2] = d2;
        ci[cb + 0] = i0; ci[cb + 1] = i1; ci[cb + 2] = i2;
        __syncthreads();

        // merge 8 eighths, ascending-eighth order, strict < insert == top_k ties
        if (threadIdx.x < 32) {
            float e0 = 3.4e38f, e1 = 3.4e38f, e2 = 3.4e38f;
            int   j0 = 0, j1 = 0, j2 = 0;
#pragma unroll
            for (int s = 0; s < 24; ++s) {
                const float d = cd[fl * 24 + s];
                const int   j = ci[fl * 24 + s];
                const bool c2 = d < e2, c1 = d < e1, c0 = d < e0;
                e2 = c1 ? e1 : (c2 ? d : e2);  j2 = c1 ? j1 : (c2 ? j : j2);
                e1 = c0 ? e0 : (c1 ? d : e1);  j1 = c0 ? j0 : (c1 ? j : j1);
                e0 = c0 ? d  : e0;             j0 = c0 ? j  : j0;
            }
            const float w0 = 1.0f / fmaxf(e0, EPS_);
            const float w1 = 1.0f / fmaxf(e1, EPS_);
            const float w2 = 1.0f / fmaxf(e2, EPS_);
            const float inv = 1.0f / (w0 + w1 + w2);
            idx3[f * 3 + 0] = b * NC + j0;
            idx3[f * 3 + 1] = b * NC + j1;
            idx3[f * 3 + 2] = b * NC + j2;
            w3[f * 3 + 0] = w0 * inv;
            w3[f * 3 + 1] = w1 * inv;
            w3[f * 3 + 2] = w2 * inv;
        }
    } else if (bid < 2689) {
        // ---- weight convert/transpose + b1 permute ----
        const int t = (bid - 2048) * 256 + threadIdx.x;
        if (t < 256 * 256) {
            const int k = t >> 8, n = t & 255;
            W1aT[n * 256 + k] = (f16)W1[k * 256 + n];
        } else if (t < 256 * 256 + 128 * 256) {
            const int u = t - 256 * 256;
            const int k = u >> 8, n = u & 255;
            W1bT[n * 128 + k] = (f16)W1[(256 + k) * 256 + n];
        } else if (t < 256 * 256 + 128 * 256 + 256 * 256) {
            const int u = t - 256 * 256 - 128 * 256;
            const int n = u >> 8, j = u & 255;
            const int k = (j & ~63) + ((j & 3) << 4) + ((j >> 2) & 15);
            W2T[n * 256 + j] = (f16)W2[k * 256 + n];
        } else if (t < 256 * 256 + 128 * 256 + 256 * 256 + 256) {
            const int j = t - (256 * 256 + 128 * 256 + 256 * 256);
            const int k = (j & ~63) + ((j & 3) << 4) + ((j >> 2) & 15);
            b1p[j] = b1[k];
        }
    } else {
        // ---- tail: pos_skip passthrough + batch_skip as float ----
        const int i = (bid - 2689) * 256 + threadIdx.x;
        const int npos = MTOT * 3;
        if (i < npos)               out_tail[i] = pos_skip[i];
        else if (i < npos + MTOT)   out_tail[i] = (float)batch_skip[i - npos];
    }
}

// ---------------- async global->LDS, 16B per lane, linear dest ----------------
__device__ __forceinline__ void gload16(const void* g, void* l)
{
    __builtin_amdgcn_global_load_lds(
        (const __attribute__((address_space(1))) unsigned int*)g,
        (__attribute__((address_space(3))) unsigned int*)l, 16, 0, 0);
}

// ---------------- y = x @ W1aT^T, K-permuted f16 store ----------------
// BM=128, BN=256, BK=64, 4 waves (2x2), wave tile 64x128. A f32 reg-staged.
__global__ __launch_bounds__(256, 2) void gemm_y(
    const float* __restrict__ A, const f16* __restrict__ Bt,
    f16* __restrict__ C)
{
    __shared__ f16 As[128 * 64];   // 16 KB
    __shared__ f16 Bs[256 * 64];   // 32 KB
    const int tid  = threadIdx.x;
    const int lane = tid & 63;
    const int wid  = tid >> 6;
    const int wr   = wid >> 1, wc = wid & 1;
    const int m0   = blockIdx.x * 128;

    const int srow = tid >> 1;
    const int scg  = tid & 1;
    const int srow_l = lane >> 3;
    const int kch    = (lane & 7) ^ ((lane >> 3) & 7);

    f32x4 acc[4][8] = {};

    for (int k0 = 0; k0 < 256; k0 += 64) {
#pragma unroll
        for (int r = 0; r < 8; ++r) {
            const int c = (wid << 3) + r;
            const int row = (c << 3) + srow_l;
            gload16(Bt + (size_t)row * 256 + k0 + kch * 8,
                    (char*)Bs + (c << 10));
        }
        {
            const float* p = A + (size_t)(m0 + srow) * 256 + k0 + scg * 32;
            float v[32];
#pragma unroll
            for (int j = 0; j < 8; ++j) {
                float4 a = ((const float4*)p)[j];
                v[j * 4 + 0] = a.x; v[j * 4 + 1] = a.y;
                v[j * 4 + 2] = a.z; v[j * 4 + 3] = a.w;
            }
#pragma unroll
            for (int j = 0; j < 4; ++j) {
                f16x8 hh;
#pragma unroll
                for (int t2 = 0; t2 < 8; ++t2) hh[t2] = (f16)v[j * 8 + t2];
                const int sphys = (scg * 4 + j) ^ (srow & 7);
                *(f16x8*)((char*)As + srow * 128 + sphys * 16) = hh;
            }
        }
        __syncthreads();

#pragma unroll
        for (int h = 0; h < 2; ++h) {
            f16x8 aF[4];
#pragma unroll
            for (int m = 0; m < 4; ++m) {
                const int row  = wr * 64 + m * 16 + (lane & 15);
                const int kg   = (h << 2) + (lane >> 4);
                const int slot = kg ^ (row & 7);
                aF[m] = *(const f16x8*)((const char*)As + row * 128 + slot * 16);
            }
#pragma unroll
            for (int n = 0; n < 8; ++n) {
                const int row  = wc * 128 + n * 16 + (lane & 15);
                const int kg   = (h << 2) + (lane >> 4);
                const int slot = kg ^ (row & 7);
                f16x8 bF = *(const f16x8*)((const char*)Bs + row * 128 + slot * 16);
#pragma unroll
                for (int m = 0; m < 4; ++m)
                    acc[m][n] = __builtin_amdgcn_mfma_f32_16x16x32_f16(
                        aF[m], bF, acc[m][n], 0, 0, 0);
            }
        }
        __syncthreads();
    }

    // packed K-permuted store: cols (g*4+n)*16+q -> stored j = g*64 + q*4 + n
    const int qq = lane & 15;
#pragma unroll
    for (int m = 0; m < 4; ++m) {
        const int rb = wr * 64 + m * 16 + ((lane >> 4) << 2);
#pragma unroll
        for (int r = 0; r < 4; ++r) {
            const int rg = m0 + rb + r;
#pragma unroll
            for (int g = 0; g < 2; ++g) {
                f16x4 hv;
#pragma unroll
                for (int n = 0; n < 4; ++n)
                    hv[n] = (f16)acc[m][g * 4 + n][r];
                *(f16x4*)&C[(size_t)rg * 256 + wc * 128 + g * 64 + qq * 4] = hv;
            }
        }
    }
}

// ---------------- fused layer-1b: h1 = relu(x_skip@W1bT + gather(y) + b1p) ----------------
__global__ __launch_bounds__(256, 2) void gemm1b_fused(
    const float* __restrict__ A, const f16* __restrict__ Bt,
    const f16* __restrict__ y,
    const int* __restrict__ idx3, const float* __restrict__ w3,
    const float* __restrict__ b1p, f16* __restrict__ h1)
{
    __shared__ f16 As[128 * 64];   // 16 KB
    __shared__ f16 Bs[256 * 64];   // 32 KB
    const int tid  = threadIdx.x;
    const int lane = tid & 63;
    const int wid  = tid >> 6;
    const int wr   = wid >> 1, wc = wid & 1;
    const int m0   = blockIdx.x * 128;

    const int srow = tid >> 1;
    const int scg  = tid & 1;
    const int srow_l = lane >> 3;
    const int kch    = (lane & 7) ^ ((lane >> 3) & 7);

    f32x4 acc[4][8] = {};

    for (int k0 = 0; k0 < 128; k0 += 64) {
#pragma unroll
        for (int r = 0; r < 8; ++r) {
            const int c = (wid << 3) + r;
            const int row = (c << 3) + srow_l;
            gload16(Bt + (size_t)row * 128 + k0 + kch * 8,
                    (char*)Bs + (c << 10));
        }
        {
            const float* p = A + (size_t)(m0 + srow) * 128 + k0 + scg * 32;
            float v[32];
#pragma unroll
            for (int j = 0; j < 8; ++j) {
                float4 a = ((const float4*)p)[j];
                v[j * 4 + 0] = a.x; v[j * 4 + 1] = a.y;
                v[j * 4 + 2] = a.z; v[j * 4 + 3] = a.w;
            }
#pragma unroll
            for (int j = 0; j < 4; ++j) {
                f16x8 hh;
#pragma unroll
                for (int t2 = 0; t2 < 8; ++t2) hh[t2] = (f16)v[j * 8 + t2];
                const int sphys = (scg * 4 + j) ^ (srow & 7);
                *(f16x8*)((char*)As + srow * 128 + sphys * 16) = hh;
            }
        }
        __syncthreads();

#pragma unroll
        for (int h = 0; h < 2; ++h) {
            f16x8 aF[4];
#pragma unroll
            for (int m = 0; m < 4; ++m) {
                const int row  = wr * 64 + m * 16 + (lane & 15);
                const int kg   = (h << 2) + (lane >> 4);
                const int slot = kg ^ (row & 7);
                aF[m] = *(const f16x8*)((const char*)As + row * 128 + slot * 16);
            }
#pragma unroll
            for (int n = 0; n < 8; ++n) {
                const int row  = wc * 128 + n * 16 + (lane & 15);
                const int kg   = (h << 2) + (lane >> 4);
                const int slot = kg ^ (row & 7);
                f16x8 bF = *(const f16x8*)((const char*)Bs + row * 128 + slot * 16);
#pragma unroll
                for (int m = 0; m < 4; ++m)
                    acc[m][n] = __builtin_amdgcn_mfma_f32_16x16x32_f16(
                        aF[m], bF, acc[m][n], 0, 0, 0);
            }
        }
        __syncthreads();
    }

    // fused epilogue: h1 = relu(acc + sum w_j*y[g_j] + b1p), permuted cols
    const int qq = lane & 15;
    const f32x4 bv0 = *(const f32x4*)&b1p[wc * 128 + qq * 4];
    const f32x4 bv1 = *(const f32x4*)&b1p[wc * 128 + 64 + qq * 4];
#pragma unroll
    for (int m = 0; m < 4; ++m) {
        const int rb = wr * 64 + m * 16 + ((lane >> 4) << 2);
#pragma unroll
        for (int r = 0; r < 4; ++r) {
            const int rg = m0 + rb + r;
            const int i0 = idx3[rg * 3 + 0], i1 = idx3[rg * 3 + 1], i2 = idx3[rg * 3 + 2];
            const float w0 = w3[rg * 3 + 0], w1 = w3[rg * 3 + 1], w2 = w3[rg * 3 + 2];
#pragma unroll
            for (int g = 0; g < 2; ++g) {
                const int jb = wc * 128 + g * 64 + qq * 4;
                f16x4 y0 = *(const f16x4*)&y[(size_t)i0 * 256 + jb];
                f16x4 y1 = *(const f16x4*)&y[(size_t)i1 * 256 + jb];
                f16x4 y2 = *(const f16x4*)&y[(size_t)i2 * 256 + jb];
                const f32x4 bv = g ? bv1 : bv0;
                f16x4 hv;
#pragma unroll
                for (int n = 0; n < 4; ++n) {
                    float v = acc[m][g * 4 + n][r]
                            + w0 * (float)y0[n] + w1 * (float)y1[n] + w2 * (float)y2[n]
                            + bv[n];
                    hv[n] = (f16)fmaxf(v, 0.0f);
                }
                *(f16x4*)&h1[(size_t)rg * 256 + jb] = hv;
            }
        }
    }
}

// ---------------- layer-2 GEMM: out = relu(h1_s @ W2T_s^T + b2), f32 standard layout ----------------
__global__ __launch_bounds__(256, 2) void gemm2_kernel(
    const f16* __restrict__ A, const f16* __restrict__ Bt,
    const float* __restrict__ bias, float* __restrict__ out)
{
    __shared__ f16 As[128 * 64];   // 16 KB
    __shared__ f16 Bs[256 * 64];   // 32 KB
    const int tid  = threadIdx.x;
    const int lane = tid & 63;
    const int wid  = tid >> 6;
    const int wr   = wid >> 1, wc = wid & 1;
    const int m0   = blockIdx.x * 128;

    const int srow_l = lane >> 3;
    const int kch    = (lane & 7) ^ ((lane >> 3) & 7);

    f32x4 acc[4][8] = {};

    for (int k0 = 0; k0 < 256; k0 += 64) {
#pragma unroll
        for (int r = 0; r < 4; ++r) {           // A: 16 chunks, 4 per wave
            const int c = (wid << 2) + r;
            const int row = (c << 3) + srow_l;
            gload16(A + (size_t)(m0 + row) * 256 + k0 + kch * 8,
                    (char*)As + (c << 10));
        }
#pragma unroll
        for (int r = 0; r < 8; ++r) {           // B: 32 chunks, 8 per wave
            const int c = (wid << 3) + r;
            const int row = (c << 3) + srow_l;
            gload16(Bt + (size_t)row * 256 + k0 + kch * 8,
                    (char*)Bs + (c << 10));
        }
        __syncthreads();

#pragma unroll
        for (int h = 0; h < 2; ++h) {
            f16x8 aF[4];
#pragma unroll
            for (int m = 0; m < 4; ++m) {
                const int row  = wr * 64 + m * 16 + (lane & 15);
                const int kg   = (h << 2) + (lane >> 4);
                const int slot = kg ^ (row & 7);
                aF[m] = *(const f16x8*)((const char*)As + row * 128 + slot * 16);
            }
#pragma unroll
            for (int n = 0; n < 8; ++n) {
                const int row  = wc * 128 + n * 16 + (lane & 15);
                const int kg   = (h << 2) + (lane >> 4);
                const int slot = kg ^ (row & 7);
                f16x8 bF = *(const f16x8*)((const char*)Bs + row * 128 + slot * 16);
#pragma unroll
                for (int m = 0; m < 4; ++m)
                    acc[m][n] = __builtin_amdgcn_mfma_f32_16x16x32_f16(
                        aF[m], bF, acc[m][n], 0, 0, 0);
            }
        }
        __syncthreads();
    }

    // standard-layout f32 store + bias + relu
#pragma unroll
    for (int m = 0; m < 4; ++m) {
#pragma unroll
        for (int n = 0; n < 8; ++n) {
            const int col = wc * 128 + n * 16 + (lane & 15);
            const float bv = bias[col];
#pragma unroll
            for (int r = 0; r < 4; ++r) {
                const int row = m0 + wr * 64 + m * 16 + ((lane >> 4) << 2) + r;
                out[(size_t)row * 256 + col] = fmaxf(acc[m][n][r] + bv, 0.0f);
            }
        }
    }
}

extern "C" void kernel_launch(void* const* d_in, const int* in_sizes, int n_in,
                              void* d_out, int out_size, void* d_ws, size_t ws_size,
                              hipStream_t stream)
{
    const float* x        = (const float*)d_in[0];
    const float* pos      = (const float*)d_in[1];
    const float* x_skip   = (const float*)d_in[2];
    const float* pos_skip = (const float*)d_in[3];
    const float* W1       = (const float*)d_in[4];
    const float* b1       = (const float*)d_in[5];
    const float* W2       = (const float*)d_in[6];
    const float* b2       = (const float*)d_in[7];
    const int*   batch_skip = (const int*)d_in[9];
    float* out = (float*)d_out;

    char* ws = (char*)d_ws;
    int*   idx3  = (int*)ws;                                 // 768 KB
    float* w3    = (float*)(ws + (1u << 20));                // 768 KB
    f16*   W1aT  = (f16*)(ws + (2u << 20));                  // 128 KB
    f16*   W1bT  = (f16*)(ws + (2u << 20) + (256u << 10));   // 64 KB
    f16*   W2T   = (f16*)(ws + (2u << 20) + (512u << 10));   // 128 KB
    float* b1p   = (float*)(ws + (2u << 20) + (768u << 10)); // 1 KB
    f16*   y     = (f16*)(ws + (4u << 20));                  // 8 MB
    f16*   h1    = (f16*)(ws + (16u << 20));                 // 32 MB

    // knn + weight-convert + output-tail, fused (mutually independent)
    misc_kernel<<<3713, 256, 0, stream>>>(
        pos, pos_skip, batch_skip, W1, W2, b1,
        idx3, w3, W1aT, W1bT, W2T, b1p, out + (size_t)MTOT * CHID);

    // y = x @ W1a   (M=16384, K=256), K-permuted store
    gemm_y<<<B_ * NC / 128, 256, 0, stream>>>(x, W1aT, y);

    // h1 = relu(x_skip @ W1b + gather(y) + b1p)  (epilogue-fused gather)
    gemm1b_fused<<<MTOT / 128, 256, 0, stream>>>(x_skip, W1bT, y, idx3, w3, b1p, h1);

    // out = relu(h1 @ W2T^T + b2)  (permutation cancels)
    gemm2_kernel<<<MTOT / 128, 256, 0, stream>>>(h1, W2T, b2, out);
}

// Round 14
// 177.669 us; speedup vs baseline: 1.4643x; 1.1175x over previous
//
#include <hip/hip_runtime.h>

#define B_ 16
#define NC 1024
#define NF 4096
#define CIN 256
#define CSKIP 128
#define CHID 256
#define MTOT (B_ * NF)   // 65536
#define EPS_ 1e-16f

typedef _Float16 f16;
typedef __attribute__((ext_vector_type(8))) _Float16 f16x8;
typedef __attribute__((ext_vector_type(4))) _Float16 f16x4;
typedef __attribute__((ext_vector_type(4))) float f32x4;

// K-permutation: stored j holds logical k(j) = (j&~63) + (j&3)*16 + ((j>>2)&15).
// y and the LDS h1 tile live in this permuted column space; W2T rows and b1p
// are permuted to match, so the layer-2 GEMM cancels the permutation exactly.

// ---------------- async global->LDS, 16B per lane, linear dest ----------------
__device__ __forceinline__ void gload16(const void* g, void* l)
{
    __builtin_amdgcn_global_load_lds(
        (const __attribute__((address_space(1))) unsigned int*)g,
        (__attribute__((address_space(3))) unsigned int*)l, 16, 0, 0);
}

// ---------------- misc: gemm_y (0..255) + knn (256..2303) + wconv (2304..2688) + tail (2689..3712) ----------------
// gemm_y first so its 256 MFMA blocks overlap the 2048 VALU-bound knn blocks.
// gemm_y stages B directly from f32 W1 (in-reg 4x4 transpose-convert) so it
// has no dependency on wconv. VGPR capped (256,4) -> knn keeps 4 blocks/CU.
__global__ __launch_bounds__(256, 4) void misc_kernel(
    const float* __restrict__ x,
    const float* __restrict__ pos, const float* __restrict__ pos_skip,
    const int* __restrict__ batch_skip,
    const float* __restrict__ W1, const float* __restrict__ W2,
    const float* __restrict__ b1,
    int* __restrict__ idx3, float* __restrict__ w3,
    f16* __restrict__ W1bT, f16* __restrict__ W2T, float* __restrict__ b1p,
    f16* __restrict__ y, float* __restrict__ out_tail)
{
    __shared__ __align__(16) char smem[32768];
    const int bid = blockIdx.x;

    if (bid < 256) {
        // ---- y = x @ W1a^T (M=16384, K=256), K-permuted f16 store ----
        // BM=128, BN=128; B staged from W1 f32 with transpose-convert.
        f16* As = (f16*)smem;              // [128][64]
        f16* Bs = (f16*)(smem + 16384);    // [128][64]
        const int m0 = (bid >> 1) * 128;
        const int n0 = (bid & 1) * 128;
        const int tid  = threadIdx.x;
        const int lane = tid & 63;
        const int wid  = tid >> 6;
        const int wr   = wid >> 1, wc = wid & 1;
        const int srow = tid >> 1;         // A-staging: 2 thr/row, 32 ch
        const int scg  = tid & 1;
        const int bn4  = (tid & 31) << 2;  // B-staging: n offset
        const int bkb  = (tid >> 5) << 3;  // B-staging: k base (8 k's)

        f32x4 acc[4][4] = {};
        for (int k0 = 0; k0 < 256; k0 += 64) {
            {   // A: x rows -> f16, swizzled ds_write
                const float* p = x + (size_t)(m0 + srow) * 256 + k0 + scg * 32;
                float v[32];
#pragma unroll
                for (int j = 0; j < 8; ++j) {
                    float4 a = ((const float4*)p)[j];
                    v[j*4+0]=a.x; v[j*4+1]=a.y; v[j*4+2]=a.z; v[j*4+3]=a.w;
                }
#pragma unroll
                for (int j = 0; j < 4; ++j) {
                    f16x8 hh;
#pragma unroll
                    for (int t2 = 0; t2 < 8; ++t2) hh[t2] = (f16)v[j*8+t2];
                    const int sphys = (scg*4 + j) ^ (srow & 7);
                    *(f16x8*)((char*)As + srow*128 + sphys*16) = hh;
                }
            }
            // B: W1[k0+k][n0+bn4..+4] 4 rows -> 4x4 transpose -> Bs[n][k], swizzled
#pragma unroll
            for (int c = 0; c < 2; ++c) {
                const int k = bkb + c * 4;
                const float* wp = W1 + (size_t)(k0 + k) * 256 + n0 + bn4;
                float4 r0 = *(const float4*)(wp);
                float4 r1 = *(const float4*)(wp + 256);
                float4 r2 = *(const float4*)(wp + 512);
                float4 r3 = *(const float4*)(wp + 768);
                const int half  = (k >> 2) & 1;
                const int kslot = k >> 3;
                f16x4 t0, t1, t2v, t3;
                t0[0]=(f16)r0.x; t0[1]=(f16)r1.x; t0[2]=(f16)r2.x; t0[3]=(f16)r3.x;
                t1[0]=(f16)r0.y; t1[1]=(f16)r1.y; t1[2]=(f16)r2.y; t1[3]=(f16)r3.y;
                t2v[0]=(f16)r0.z; t2v[1]=(f16)r1.z; t2v[2]=(f16)r2.z; t2v[3]=(f16)r3.z;
                t3[0]=(f16)r0.w; t3[1]=(f16)r1.w; t3[2]=(f16)r2.w; t3[3]=(f16)r3.w;
                *(f16x4*)((char*)Bs + (bn4+0)*128 + ((kslot ^ ((bn4+0)&7))*16) + half*8) = t0;
                *(f16x4*)((char*)Bs + (bn4+1)*128 + ((kslot ^ ((bn4+1)&7))*16) + half*8) = t1;
                *(f16x4*)((char*)Bs + (bn4+2)*128 + ((kslot ^ ((bn4+2)&7))*16) + half*8) = t2v;
                *(f16x4*)((char*)Bs + (bn4+3)*128 + ((kslot ^ ((bn4+3)&7))*16) + half*8) = t3;
            }
            __syncthreads();
#pragma unroll
            for (int h = 0; h < 2; ++h) {
                f16x8 aF[4], bF[4];
#pragma unroll
                for (int m = 0; m < 4; ++m) {
                    const int row  = wr*64 + m*16 + (lane & 15);
                    const int kg   = (h<<2) + (lane>>4);
                    const int slot = kg ^ (row & 7);
                    aF[m] = *(const f16x8*)((const char*)As + row*128 + slot*16);
                }
#pragma unroll
                for (int n = 0; n < 4; ++n) {
                    const int row  = wc*64 + n*16 + (lane & 15);
                    const int kg   = (h<<2) + (lane>>4);
                    const int slot = kg ^ (row & 7);
                    bF[n] = *(const f16x8*)((const char*)Bs + row*128 + slot*16);
                }
#pragma unroll
                for (int m = 0; m < 4; ++m)
#pragma unroll
                    for (int n = 0; n < 4; ++n)
                        acc[m][n] = __builtin_amdgcn_mfma_f32_16x16x32_f16(
                            aF[m], bF[n], acc[m][n], 0, 0, 0);
            }
            __syncthreads();
        }
        // packed K-permuted store: col n*16+q -> stored j = q*4+n (within 64-group)
        const int qq = lane & 15;
#pragma unroll
        for (int m = 0; m < 4; ++m) {
            const int rb = wr*64 + m*16 + ((lane>>4) << 2);
#pragma unroll
            for (int r = 0; r < 4; ++r) {
                const int rg = m0 + rb + r;
                f16x4 hv;
#pragma unroll
                for (int n = 0; n < 4; ++n) hv[n] = (f16)acc[m][n][r];
                *(f16x4*)&y[(size_t)rg * 256 + n0 + wc*64 + qq*4] = hv;
            }
        }
    } else if (bid < 2304) {
        // ---- kNN top-3: 32 fine x 8 coarse-eighths, exact d^2 (round-12-proven) ----
        float4* cpos = (float4*)smem;               // 16 KB
        float*  cd   = (float*)(smem + 16384);      // 3 KB
        int*    ci   = (int*)(smem + 19456);        // 3 KB
        const int kb = bid - 256;
        const int b  = kb >> 7;
        const int fb = kb & 127;
        const float* cp = pos + (size_t)b * NC * 3;
        for (int i = threadIdx.x; i < NC; i += 256)
            cpos[i] = make_float4(cp[i*3], cp[i*3+1], cp[i*3+2], 0.0f);
        __syncthreads();

        const int fl = threadIdx.x & 31;
        const int q  = threadIdx.x >> 5;
        const int f  = b * NF + fb * 32 + fl;
        const float px = pos_skip[f*3+0];
        const float py = pos_skip[f*3+1];
        const float pz = pos_skip[f*3+2];

        float d0 = 3.4e38f, d1 = 3.4e38f, d2 = 3.4e38f;
        int   i0 = 0, i1 = 0, i2 = 0;
        const int jbase = q << 7;
#pragma unroll 4
        for (int jj = 0; jj < 128; ++jj) {
            const int j = jbase + jj;
            float4 c = cpos[j];
            float dx = px - c.x, dy = py - c.y, dz = pz - c.z;
            float d = fmaf(dx, dx, fmaf(dy, dy, dz * dz));
            const bool c2 = d < d2, c1 = d < d1, c0 = d < d0;
            d2 = c1 ? d1 : (c2 ? d : d2);  i2 = c1 ? i1 : (c2 ? j : i2);
            d1 = c0 ? d0 : (c1 ? d : d1);  i1 = c0 ? i0 : (c1 ? j : i1);
            d0 = c0 ? d  : d0;             i0 = c0 ? j  : i0;
        }
        const int cb = fl * 24 + q * 3;
        cd[cb+0] = d0; cd[cb+1] = d1; cd[cb+2] = d2;
        ci[cb+0] = i0; ci[cb+1] = i1; ci[cb+2] = i2;
        __syncthreads();

        if (threadIdx.x < 32) {
            float e0 = 3.4e38f, e1 = 3.4e38f, e2 = 3.4e38f;
            int   j0 = 0, j1 = 0, j2 = 0;
#pragma unroll
            for (int s = 0; s < 24; ++s) {
                const float d = cd[fl*24 + s];
                const int   j = ci[fl*24 + s];
                const bool c2 = d < e2, c1 = d < e1, c0 = d < e0;
                e2 = c1 ? e1 : (c2 ? d : e2);  j2 = c1 ? j1 : (c2 ? j : j2);
                e1 = c0 ? e0 : (c1 ? d : e1);  j1 = c0 ? j0 : (c1 ? j : j1);
                e0 = c0 ? d  : e0;             j0 = c0 ? j  : j0;
            }
            const float w0 = 1.0f / fmaxf(e0, EPS_);
            const float w1 = 1.0f / fmaxf(e1, EPS_);
            const float w2 = 1.0f / fmaxf(e2, EPS_);
            const float inv = 1.0f / (w0 + w1 + w2);
            idx3[f*3+0] = b * NC + j0;
            idx3[f*3+1] = b * NC + j1;
            idx3[f*3+2] = b * NC + j2;
            w3[f*3+0] = w0 * inv;
            w3[f*3+1] = w1 * inv;
            w3[f*3+2] = w2 * inv;
        }
    } else if (bid < 2689) {
        // ---- wconv: W1bT [256][128], W2T [256][256] (K-perm rows), b1p ----
        const int t = (bid - 2304) * 256 + threadIdx.x;
        if (t < 128 * 256) {
            const int k = t >> 8, n = t & 255;        // k in [0,128)
            W1bT[n * 128 + k] = (f16)W1[(256 + k) * 256 + n];
        } else if (t < 128 * 256 + 256 * 256) {
            const int u = t - 128 * 256;
            const int n = u >> 8, j = u & 255;
            const int k = (j & ~63) + ((j & 3) << 4) + ((j >> 2) & 15);
            W2T[n * 256 + j] = (f16)W2[k * 256 + n];
        } else if (t < 128 * 256 + 256 * 256 + 256) {
            const int j = t - (128 * 256 + 256 * 256);
            const int k = (j & ~63) + ((j & 3) << 4) + ((j >> 2) & 15);
            b1p[j] = b1[k];
        }
    } else {
        // ---- tail: pos_skip passthrough + batch_skip as float ----
        const int i = (bid - 2689) * 256 + threadIdx.x;
        const int npos = MTOT * 3;
        if (i < npos)               out_tail[i] = pos_skip[i];
        else if (i < npos + MTOT)   out_tail[i] = (float)batch_skip[i - npos];
    }
}

// ---------------- fused layers 1b+2: out = relu( relu(x_skip@W1bT + gather(y) + b1p) @ W2T + b2 ) ----------------
// BM=64, BN=256, 1024 blocks, 64KB LDS (Bs 32K | As 8K overlaid by h1s 32K),
// 2 blocks/CU. h1 tile lives in LDS (saves the 64 MB h1 HBM round-trip).
// h1s swizzle: phys_slot = (s&~7) | ((s&7) ^ (row&7)), s = byte/16 within row.
__global__ __launch_bounds__(256, 2) void fused_gemm12(
    const float* __restrict__ A,      // x_skip [M][128]
    const f16* __restrict__ B1t,      // W1bT [256][128]
    const f16* __restrict__ y,        // [16384][256], permuted cols
    const int* __restrict__ idx3, const float* __restrict__ w3,
    const float* __restrict__ b1p,    // permuted
    const f16* __restrict__ B2t,      // W2T [256][256], rows n2, cols permuted j
    const float* __restrict__ b2,
    float* __restrict__ out)
{
    __shared__ __align__(16) char lds[65536];
    f16*  Bs  = (f16*)lds;            // [256][64], both loops
    f16*  As  = (f16*)(lds + 32768);  // [64][64], loop1 only
    char* h1s = lds + 32768;          // [64][256] f16, from mid-epilogue on

    const int tid  = threadIdx.x;
    const int lane = tid & 63;
    const int wid  = tid >> 6;
    const int wr   = wid >> 1, wc = wid & 1;
    const int m0   = blockIdx.x * 64;

    const int srow_l = lane >> 3;
    const int kch    = (lane & 7) ^ ((lane >> 3) & 7);

    // ---- loop1: acc = x_skip @ W1bT^T  (K=128) ----
    f32x4 acc[2][8] = {};
    for (int k0 = 0; k0 < 128; k0 += 64) {
#pragma unroll
        for (int r = 0; r < 8; ++r) {            // B: 32 chunks, 8/wave
            const int c = (wid << 3) + r;
            const int row = (c << 3) + srow_l;
            gload16(B1t + (size_t)row * 128 + k0 + kch * 8, (char*)Bs + (c << 10));
        }
        {   // A: 4 thr/row, 16 ch each -> f16 swizzled
            const int arow = tid >> 2, acg = tid & 3;
            const float* p = A + (size_t)(m0 + arow) * 128 + k0 + acg * 16;
            float v[16];
#pragma unroll
            for (int j = 0; j < 4; ++j) {
                float4 a = ((const float4*)p)[j];
                v[j*4+0]=a.x; v[j*4+1]=a.y; v[j*4+2]=a.z; v[j*4+3]=a.w;
            }
#pragma unroll
            for (int j = 0; j < 2; ++j) {
                f16x8 hh;
#pragma unroll
                for (int t2 = 0; t2 < 8; ++t2) hh[t2] = (f16)v[j*8+t2];
                const int sphys = (acg*2 + j) ^ (arow & 7);
                *(f16x8*)((char*)As + arow*128 + sphys*16) = hh;
            }
        }
        __syncthreads();
#pragma unroll
        for (int h = 0; h < 2; ++h) {
            f16x8 aF[2];
#pragma unroll
            for (int m = 0; m < 2; ++m) {
                const int row  = wr*32 + m*16 + (lane & 15);
                const int kg   = (h<<2) + (lane>>4);
                const int slot = kg ^ (row & 7);
                aF[m] = *(const f16x8*)((const char*)As + row*128 + slot*16);
            }
#pragma unroll
            for (int n = 0; n < 8; ++n) {
                const int row  = wc*128 + n*16 + (lane & 15);
                const int kg   = (h<<2) + (lane>>4);
                const int slot = kg ^ (row & 7);
                f16x8 bF = *(const f16x8*)((const char*)Bs + row*128 + slot*16);
#pragma unroll
                for (int m = 0; m < 2; ++m)
                    acc[m][n] = __builtin_amdgcn_mfma_f32_16x16x32_f16(
                        aF[m], bF, acc[m][n], 0, 0, 0);
            }
        }
        __syncthreads();
    }

    // ---- mid-epilogue: h1s = relu(acc + sum w_j*y[g_j] + b1p), swizzled LDS ----
    const int qq = lane & 15;
    const f32x4 bv0 = *(const f32x4*)&b1p[wc*128 + qq*4];
    const f32x4 bv1 = *(const f32x4*)&b1p[wc*128 + 64 + qq*4];
#pragma unroll
    for (int m = 0; m < 2; ++m) {
        const int rb = wr*32 + m*16 + ((lane>>4) << 2);
#pragma unroll
        for (int r = 0; r < 4; ++r) {
            const int rl = rb + r;               // local row 0..63
            const int rg = m0 + rl;
            const int i0 = idx3[rg*3+0], i1 = idx3[rg*3+1], i2 = idx3[rg*3+2];
            const float w0 = w3[rg*3+0], w1 = w3[rg*3+1], w2 = w3[rg*3+2];
#pragma unroll
            for (int g = 0; g < 2; ++g) {
                const int jb = wc*128 + g*64 + qq*4;
                f16x4 y0 = *(const f16x4*)&y[(size_t)i0 * 256 + jb];
                f16x4 y1 = *(const f16x4*)&y[(size_t)i1 * 256 + jb];
                f16x4 y2 = *(const f16x4*)&y[(size_t)i2 * 256 + jb];
                const f32x4 bv = g ? bv1 : bv0;
                f16x4 hv;
#pragma unroll
                for (int n = 0; n < 4; ++n) {
                    float v = acc[m][g*4+n][r]
                            + w0*(float)y0[n] + w1*(float)y1[n] + w2*(float)y2[n]
                            + bv[n];
                    hv[n] = (f16)fmaxf(v, 0.0f);
                }
                const int slot = jb >> 3;
                const int phys = (slot & ~7) | ((slot & 7) ^ (rl & 7));
                *(f16x4*)(h1s + rl*512 + phys*16 + ((jb >> 2) & 1) * 8) = hv;
            }
        }
    }
    __syncthreads();

    // ---- loop2: acc2 = h1s @ W2T^T  (K=256, A from LDS) ----
    f32x4 acc2[2][8] = {};
    for (int k0 = 0; k0 < 256; k0 += 64) {
#pragma unroll
        for (int r = 0; r < 8; ++r) {            // B: 32 chunks, 8/wave
            const int c = (wid << 3) + r;
            const int row = (c << 3) + srow_l;
            gload16(B2t + (size_t)row * 256 + k0 + kch * 8, (char*)Bs + (c << 10));
        }
        __syncthreads();
#pragma unroll
        for (int h = 0; h < 2; ++h) {
            f16x8 aF[2];
#pragma unroll
            for (int m = 0; m < 2; ++m) {
                const int row   = wr*32 + m*16 + (lane & 15);
                const int kg    = (h<<2) + (lane>>4);
                const int aslot = (k0 >> 3) + (kg ^ (row & 7));
                aF[m] = *(const f16x8*)(h1s + row*512 + aslot*16);
            }
#pragma unroll
            for (int n = 0; n < 8; ++n) {
                const int row  = wc*128 + n*16 + (lane & 15);
                const int kg   = (h<<2) + (lane>>4);
                const int slot = kg ^ (row & 7);
                f16x8 bF = *(const f16x8*)((const char*)Bs + row*128 + slot*16);
#pragma unroll
                for (int m = 0; m < 2; ++m)
                    acc2[m][n] = __builtin_amdgcn_mfma_f32_16x16x32_f16(
                        aF[m], bF, acc2[m][n], 0, 0, 0);
            }
        }
        __syncthreads();
    }

    // ---- final epilogue: out = relu(acc2 + b2), f32 standard layout ----
#pragma unroll
    for (int m = 0; m < 2; ++m) {
#pragma unroll
        for (int n = 0; n < 8; ++n) {
            const int col = wc*128 + n*16 + (lane & 15);
            const float bv = b2[col];
#pragma unroll
            for (int r = 0; r < 4; ++r) {
                const int row = m0 + wr*32 + m*16 + ((lane>>4) << 2) + r;
                out[(size_t)row * 256 + col] = fmaxf(acc2[m][n][r] + bv, 0.0f);
            }
        }
    }
}

extern "C" void kernel_launch(void* const* d_in, const int* in_sizes, int n_in,
                              void* d_out, int out_size, void* d_ws, size_t ws_size,
                              hipStream_t stream)
{
    const float* x        = (const float*)d_in[0];
    const float* pos      = (const float*)d_in[1];
    const float* x_skip   = (const float*)d_in[2];
    const float* pos_skip = (const float*)d_in[3];
    const float* W1       = (const float*)d_in[4];
    const float* b1       = (const float*)d_in[5];
    const float* W2       = (const float*)d_in[6];
    const float* b2       = (const float*)d_in[7];
    const int*   batch_skip = (const int*)d_in[9];
    float* out = (float*)d_out;

    char* ws = (char*)d_ws;
    int*   idx3 = (int*)ws;                                  // 768 KB
    float* w3   = (float*)(ws + (1u << 20));                 // 768 KB
    f16*   W1bT = (f16*)(ws + (2u << 20));                   // 64 KB
    f16*   W2T  = (f16*)(ws + (2u << 20) + (256u << 10));    // 128 KB
    float* b1p  = (float*)(ws + (2u << 20) + (512u << 10));  // 1 KB
    f16*   y    = (f16*)(ws + (4u << 20));                   // 8 MB

    // gemm_y + knn + wconv + tail in one launch (gemm_y blocks first -> overlap knn)
    misc_kernel<<<3713, 256, 0, stream>>>(
        x, pos, pos_skip, batch_skip, W1, W2, b1,
        idx3, w3, W1bT, W2T, b1p, y, out + (size_t)MTOT * CHID);

    // fused layer1b + gather + layer2 (h1 tile LDS-resident)
    fused_gemm12<<<MTOT / 64, 256, 0, stream>>>(
        x_skip, W1bT, y, idx3, w3, b1p, W2T, b2, out);
}